// Round 7
// baseline (200.481 us; speedup 1.0000x reference)
//
#include <hip/hip_runtime.h>

#define Dm 1024
#define Lq 128
#define Bq 8
#define Hh 16
#define HDim 64

typedef __attribute__((ext_vector_type(8))) short bf16x8;
typedef __attribute__((ext_vector_type(4))) float f32x4;
typedef unsigned short ushort_t;

#define GLOAD16(gp, lp) __builtin_amdgcn_global_load_lds( \
    (const __attribute__((address_space(1))) void*)(gp), \
    (__attribute__((address_space(3))) void*)(lp), 16, 0, 0)

__device__ __forceinline__ unsigned short bf16h(float x) {
    unsigned u = __float_as_uint(x);
    return (unsigned short)((u + 0x7FFFu + ((u >> 16) & 1u)) >> 16);
}
__device__ __forceinline__ float bf16f(unsigned short s) {
    return __uint_as_float(((unsigned)s) << 16);
}

// ---------------------------------------------------------------------------
// convert5: fp32 -> (bf16 hi, bf16 lo) for {query, Wq, Wk, Wv, Wo} (1M each)
// ---------------------------------------------------------------------------
__global__ __launch_bounds__(256) void convert5_kernel(
    const float* __restrict__ s0, const float* __restrict__ s1, const float* __restrict__ s2,
    const float* __restrict__ s3, const float* __restrict__ s4,
    ushort_t* __restrict__ d0h, ushort_t* __restrict__ d0l,
    ushort_t* __restrict__ d1h, ushort_t* __restrict__ d1l,
    ushort_t* __restrict__ d2h, ushort_t* __restrict__ d2l,
    ushort_t* __restrict__ d3h, ushort_t* __restrict__ d3l,
    ushort_t* __restrict__ d4h, ushort_t* __restrict__ d4l)
{
    const int z = blockIdx.z;
    const float* src = (z == 0) ? s0 : (z == 1) ? s1 : (z == 2) ? s2 : (z == 3) ? s3 : s4;
    ushort_t* dh = (z == 0) ? d0h : (z == 1) ? d1h : (z == 2) ? d2h : (z == 3) ? d3h : d4h;
    ushort_t* dl = (z == 0) ? d0l : (z == 1) ? d1l : (z == 2) ? d2l : (z == 3) ? d3l : d4l;
    const int idx = (blockIdx.x * 256 + threadIdx.x) * 8;
    const float4 a = *(const float4*)(src + idx);
    const float4 b = *(const float4*)(src + idx + 4);
    float xs[8] = {a.x, a.y, a.z, a.w, b.x, b.y, b.z, b.w};
    unsigned hp[4], lp[4];
    #pragma unroll
    for (int e = 0; e < 4; ++e) {
        unsigned short h0 = bf16h(xs[2*e]), h1 = bf16h(xs[2*e+1]);
        unsigned short l0 = bf16h(xs[2*e]   - bf16f(h0));
        unsigned short l1 = bf16h(xs[2*e+1] - bf16f(h1));
        hp[e] = (unsigned)h0 | ((unsigned)h1 << 16);
        lp[e] = (unsigned)l0 | ((unsigned)l1 << 16);
    }
    *(int4*)(dh + idx) = *(int4*)hp;
    *(int4*)(dl + idx) = *(int4*)lp;
}

// ---------------------------------------------------------------------------
// gemm4: OUT[r,c] = sum_k X[r,k]*W[c,k] via bf16 hi/lo 3-pass MFMA.
// 128x128 tile, 8 waves (2x4 of 64x32), BK=32, single-buffered LINEAR LDS
// staged with global_load_lds width=16 (m97 structure). Thread t <-> row t>>2,
// chunk t&3: LDS dest = base + t*16B (wave-uniform base + lane*16 respected).
// mode 0: bf16 hi/lo outputs (z selects W/O; bias on z==0). mode 1: fp32.
// ---------------------------------------------------------------------------
__global__ __launch_bounds__(512) void gemm4_kernel(
    const ushort_t* __restrict__ Xhi, const ushort_t* __restrict__ Xlo,
    const ushort_t* __restrict__ W0h, const ushort_t* __restrict__ W0l,
    const ushort_t* __restrict__ W1h, const ushort_t* __restrict__ W1l,
    const ushort_t* __restrict__ W2h, const ushort_t* __restrict__ W2l,
    ushort_t* __restrict__ O0h, ushort_t* __restrict__ O0l,
    ushort_t* __restrict__ O1h, ushort_t* __restrict__ O1l,
    ushort_t* __restrict__ O2h, ushort_t* __restrict__ O2l,
    float* __restrict__ Ofp, const float* __restrict__ bias, int mode)
{
    const int z = blockIdx.z;
    const ushort_t* Wh = (z == 0) ? W0h : (z == 1) ? W1h : W2h;
    const ushort_t* Wl = (z == 0) ? W0l : (z == 1) ? W1l : W2l;
    ushort_t* Ohi = (z == 0) ? O0h : (z == 1) ? O1h : O2h;
    ushort_t* Olo = (z == 0) ? O0l : (z == 1) ? O1l : O2l;

    __shared__ __align__(16) ushort_t Ah[128 * 32];   // 8 KB each, 32 KB total
    __shared__ __align__(16) ushort_t Al[128 * 32];
    __shared__ __align__(16) ushort_t Bh[128 * 32];
    __shared__ __align__(16) ushort_t Bl[128 * 32];

    const int t = threadIdx.x, w = t >> 6, l = t & 63;
    const int r0 = blockIdx.y * 128, c0 = blockIdx.x * 128;
    const int wr = w >> 2, wc = w & 3;              // wave -> 64x32 region
    const int lc = l & 15, lg = l >> 4, lk = lg * 8;

    const size_t xg = (size_t)(r0 + (t >> 2)) * Dm + (t & 3) * 8;
    const size_t wg = (size_t)(c0 + (t >> 2)) * Dm + (t & 3) * 8;
    ushort_t* la = &Ah[t * 8];
    ushort_t* lal = &Al[t * 8];
    ushort_t* lb = &Bh[t * 8];
    ushort_t* lbl = &Bl[t * 8];

    f32x4 acc[4][2];
    #pragma unroll
    for (int m = 0; m < 4; ++m)
        #pragma unroll
        for (int n = 0; n < 2; ++n)
            acc[m][n] = (f32x4){0.f, 0.f, 0.f, 0.f};

    for (int kt = 0; kt < Dm; kt += 32) {
        __syncthreads();                 // previous compute done before overwrite
        GLOAD16(Xhi + xg + kt, la);
        GLOAD16(Xlo + xg + kt, lal);
        GLOAD16(Wh + wg + kt, lb);
        GLOAD16(Wl + wg + kt, lbl);
        __syncthreads();                 // compiler drains vmcnt before barrier

        bf16x8 a_h[4], a_l[4], b_h[2], b_l[2];
        #pragma unroll
        for (int m = 0; m < 4; ++m) {
            const int row = wr * 64 + m * 16 + lc;
            a_h[m] = *(bf16x8*)&Ah[row * 32 + lk];
            a_l[m] = *(bf16x8*)&Al[row * 32 + lk];
        }
        #pragma unroll
        for (int n = 0; n < 2; ++n) {
            const int col = wc * 32 + n * 16 + lc;
            b_h[n] = *(bf16x8*)&Bh[col * 32 + lk];
            b_l[n] = *(bf16x8*)&Bl[col * 32 + lk];
        }
        #pragma unroll
        for (int m = 0; m < 4; ++m)
            #pragma unroll
            for (int n = 0; n < 2; ++n) {
                acc[m][n] = __builtin_amdgcn_mfma_f32_16x16x32_bf16(a_h[m], b_h[n], acc[m][n], 0, 0, 0);
                acc[m][n] = __builtin_amdgcn_mfma_f32_16x16x32_bf16(a_l[m], b_h[n], acc[m][n], 0, 0, 0);
                acc[m][n] = __builtin_amdgcn_mfma_f32_16x16x32_bf16(a_h[m], b_l[n], acc[m][n], 0, 0, 0);
            }
    }

    float bz[2] = {0.f, 0.f};
    if (mode == 0 && z == 0 && bias != nullptr) {
        #pragma unroll
        for (int n = 0; n < 2; ++n)
            bz[n] = bias[c0 + wc * 32 + n * 16 + lc];
    }
    #pragma unroll
    for (int m = 0; m < 4; ++m)
        #pragma unroll
        for (int n = 0; n < 2; ++n)
            #pragma unroll
            for (int q = 0; q < 4; ++q) {
                const int r = r0 + wr * 64 + m * 16 + lg * 4 + q;
                const int c = c0 + wc * 32 + n * 16 + lc;
                float v = acc[m][n][q] + bz[n];
                const size_t oa = (size_t)r * Dm + c;
                if (mode == 1) {
                    Ofp[oa] = v;
                } else {
                    const unsigned short hh = bf16h(v);
                    Ohi[oa] = hh;
                    Olo[oa] = bf16h(v - bf16f(hh));
                }
            }
}

// ---------------------------------------------------------------------------
// wse[h,k] = sum_hd Wr[h*64+hd, k] * spk_emb[0, h*64+hd]    (16 x 1024), fp32
// ---------------------------------------------------------------------------
__global__ __launch_bounds__(256) void wse_kernel(
    const float* __restrict__ Wr, const float* __restrict__ spk_emb,
    float* __restrict__ WSE)
{
    __shared__ float se[64];
    const int t = threadIdx.x;
    const int h = blockIdx.x >> 2;
    const int k = (blockIdx.x & 3) * 256 + t;
    if (t < 64) se[t] = spk_emb[h * 64 + t];
    __syncthreads();
    float s = 0.f;
    #pragma unroll 8
    for (int hd = 0; hd < 64; ++hd)
        s += Wr[(h * 64 + hd) * Dm + k] * se[hd];
    WSE[h * Dm + k] = s;
}

// ---------------------------------------------------------------------------
// g[p, h] = sum_k rel_pe[p, k] * wse[h, k]    (1024 x 16), fp32
// ---------------------------------------------------------------------------
__global__ __launch_bounds__(256) void g_kernel(
    const float* __restrict__ rel_pe, const float* __restrict__ WSE,
    float* __restrict__ G)
{
    __shared__ float rp[1024];
    const int t = threadIdx.x;
    const int p = blockIdx.x;
    ((float4*)rp)[t] = ((const float4*)(rel_pe + p * Dm))[t];
    __syncthreads();
    const int h = t >> 4, part = t & 15;
    float s = 0.f;
    #pragma unroll 8
    for (int m = 0; m < 64; ++m) {
        const int kk = part + (m << 4);
        s += rp[kk] * WSE[h * Dm + kk];
    }
    s += __shfl_down(s, 8, 16);
    s += __shfl_down(s, 4, 16);
    s += __shfl_down(s, 2, 16);
    s += __shfl_down(s, 1, 16);
    if (part == 0) G[p * 16 + h] = s;
}

// ---------------------------------------------------------------------------
// transposeV: per (b,h) slice, V [j=128][hd=64] -> Vt [hd=64][j=128]
// (hi/lo selected by blockIdx.y). Coalesced both sides via LDS tile.
// ---------------------------------------------------------------------------
__global__ __launch_bounds__(256) void transposeV_kernel(
    const ushort_t* __restrict__ Vhi, const ushort_t* __restrict__ Vlo,
    ushort_t* __restrict__ VtHi, ushort_t* __restrict__ VtLo)
{
    __shared__ __align__(16) ushort_t T[128 * 72];
    const int blk = blockIdx.x;
    const int b = blk >> 4, h = blk & 15;
    const ushort_t* src = blockIdx.y ? Vlo : Vhi;
    ushort_t* dst = blockIdx.y ? VtLo : VtHi;
    const int t = threadIdx.x;
    #pragma unroll
    for (int it = 0; it < 4; ++it) {
        const int task = it * 256 + t;
        const int j = task >> 3, hc = (task & 7) * 8;
        *(int4*)&T[j * 72 + hc] = *(const int4*)(src + (size_t)(j * 8 + b) * 1024 + h * 64 + hc);
    }
    __syncthreads();
    #pragma unroll
    for (int it = 0; it < 4; ++it) {
        const int task = it * 256 + t;
        const int hd = task >> 4, jc = (task & 15) * 8;
        ushort_t tmp[8];
        #pragma unroll
        for (int e = 0; e < 8; ++e) tmp[e] = T[(jc + e) * 72 + hd];
        *(int4*)(dst + ((size_t)(b * 16 + h) * 64 + hd) * 128 + jc) = *(int4*)tmp;
    }
}

// ---------------------------------------------------------------------------
// attn3: MFMA attention. Block = (b,h,ihalf): 64 q-rows x 128 kv. 4 waves,
// each wave a 16-row strip. QK^T and PV via 16x16x32 bf16 MFMA hi/lo 3-pass;
// softmax on accumulator fragments (row = 16 lanes x 8 tiles). (validated r6)
// ---------------------------------------------------------------------------
__global__ __launch_bounds__(256) void attn3_kernel(
    const ushort_t* __restrict__ NQhi, const ushort_t* __restrict__ NQlo,
    const ushort_t* __restrict__ Khi,  const ushort_t* __restrict__ Klo,
    const ushort_t* __restrict__ VtHi, const ushort_t* __restrict__ VtLo,
    const float* __restrict__ G, const int* __restrict__ SM,
    const float* __restrict__ spk_emb,
    ushort_t* __restrict__ Ahi, ushort_t* __restrict__ Alo)
{
    __shared__ __align__(16) ushort_t KP[18432];  // Kh|Kl, later Ph|Pl
    __shared__ __align__(16) ushort_t QV[9216];   // Qh|Ql, later Vth|Vtl
    __shared__ float cp[128];
    __shared__ float Es[128];      // E[r][m] = Es[r*2+m]
    __shared__ float se[128];
    __shared__ float zin[64];
    __shared__ unsigned SMw[256];  // [r][word]

    const int blk = blockIdx.x, n = blk >> 1, ihalf = blk & 1;
    const int b = n >> 4, h = n & 15;
    const int t = threadIdx.x, w = t >> 6, l = t & 63;
    const int lc = l & 15, lg = l >> 4;
    const int r0w = w * 16;

    ushort_t* Kh = KP;            ushort_t* Kl = KP + 9216;
    ushort_t* Qh = QV;            ushort_t* Ql = QV + 4608;

    // ---- phase 0: staging ----
    #pragma unroll
    for (int it = 0; it < 2; ++it) {           // Q: 64 rows x 8 chunks
        const int task = it * 256 + t;
        const int r = task >> 3, col = (task & 7) * 8;
        const size_t g0 = (size_t)((ihalf * 64 + r) * 8 + b) * 1024 + h * 64 + col;
        *(int4*)&Qh[r * 72 + col] = *(const int4*)(NQhi + g0);
        *(int4*)&Ql[r * 72 + col] = *(const int4*)(NQlo + g0);
    }
    #pragma unroll
    for (int it = 0; it < 4; ++it) {           // K: 128 rows x 8 chunks
        const int task = it * 256 + t;
        const int j = task >> 3, col = (task & 7) * 8;
        const size_t g0 = (size_t)(j * 8 + b) * 1024 + h * 64 + col;
        *(int4*)&Kh[j * 72 + col] = *(const int4*)(Khi + g0);
        *(int4*)&Kl[j * 72 + col] = *(const int4*)(Klo + g0);
    }
    {   // spk-mask bit pack: r = t>>2, word = t&3
        const int r = t >> 2, wd = t & 3;
        const int i_glob = ihalf * 64 + r;
        const int* sp = SM + ((size_t)b * 128 + i_glob) * 128 + wd * 32;
        unsigned bits = 0;
        #pragma unroll
        for (int e8 = 0; e8 < 8; ++e8) {
            const int4 v = *(const int4*)(sp + e8 * 4);
            bits |= (v.x != 0 ? 1u : 0u) << (e8 * 4 + 0);
            bits |= (v.y != 0 ? 1u : 0u) << (e8 * 4 + 1);
            bits |= (v.z != 0 ? 1u : 0u) << (e8 * 4 + 2);
            bits |= (v.w != 0 ? 1u : 0u) << (e8 * 4 + 3);
        }
        SMw[r * 4 + wd] = bits;
    }
    if (t < 128) {
        cp[t] = G[((((t >> 4) << 7) + ((t & 15) << 3) + b) << 4) + h];
        se[t] = spk_emb[(t >> 6) * 1024 + h * 64 + (t & 63)];
    }
    __syncthreads();

    // ---- phase 1: QK^T MFMA + speaker dots E ----
    f32x4 acc[8];
    #pragma unroll
    for (int jt = 0; jt < 8; ++jt) acc[jt] = (f32x4){0.f, 0.f, 0.f, 0.f};
    #pragma unroll
    for (int ks = 0; ks < 2; ++ks) {
        const bf16x8 a_h = *(bf16x8*)&Qh[(r0w + lc) * 72 + ks * 32 + lg * 8];
        const bf16x8 a_l = *(bf16x8*)&Ql[(r0w + lc) * 72 + ks * 32 + lg * 8];
        #pragma unroll
        for (int jt = 0; jt < 8; ++jt) {
            const bf16x8 b_h = *(bf16x8*)&Kh[(jt * 16 + lc) * 72 + ks * 32 + lg * 8];
            const bf16x8 b_l = *(bf16x8*)&Kl[(jt * 16 + lc) * 72 + ks * 32 + lg * 8];
            acc[jt] = __builtin_amdgcn_mfma_f32_16x16x32_bf16(a_h, b_h, acc[jt], 0, 0, 0);
            acc[jt] = __builtin_amdgcn_mfma_f32_16x16x32_bf16(a_l, b_h, acc[jt], 0, 0, 0);
            acc[jt] = __builtin_amdgcn_mfma_f32_16x16x32_bf16(a_h, b_l, acc[jt], 0, 0, 0);
        }
    }
    {   // E[r][m] = new_q[r] . spk_emb[m] (per-head slice)
        const int r = t >> 2, m = (t >> 1) & 1, half = t & 1;
        float v = 0.f;
        #pragma unroll
        for (int e = 0; e < 32; ++e) {
            const int hd = half * 32 + e;
            const float qf = bf16f(Qh[r * 72 + hd]) + bf16f(Ql[r * 72 + hd]);
            v += qf * se[m * 64 + hd];
        }
        v += __shfl_xor(v, 1);
        if (half == 0) Es[r * 2 + m] = v;
    }
    __syncthreads();

    // ---- phase 2: softmax in fragments; write P hi/lo; stage Vt chunk 0 ----
    ushort_t* Ph = KP;            ushort_t* Pl = KP + 8704;
    ushort_t* Vth = QV;           ushort_t* Vtl = QV + 4608;
    #pragma unroll
    for (int q = 0; q < 4; ++q) {
        const int r = r0w + lg * 4 + q;
        const int i_glob = ihalf * 64 + r;
        const float e0 = Es[r * 2 + 0], e1 = Es[r * 2 + 1];
        float s[8];
        #pragma unroll
        for (int jt = 0; jt < 8; ++jt) {
            const int j = jt * 16 + lc;
            if (j > i_glob) {
                s[jt] = 1e-30f;
            } else {
                const unsigned bit = (SMw[r * 4 + (jt >> 1)] >> ((jt & 1) * 16 + lc)) & 1u;
                s[jt] = (acc[jt][q] + (bit ? e1 : e0) + cp[127 + j - i_glob]) * 0.125f;
            }
        }
        float mx = s[0];
        #pragma unroll
        for (int jt = 1; jt < 8; ++jt) mx = fmaxf(mx, s[jt]);
        mx = fmaxf(mx, __shfl_xor(mx, 1));
        mx = fmaxf(mx, __shfl_xor(mx, 2));
        mx = fmaxf(mx, __shfl_xor(mx, 4));
        mx = fmaxf(mx, __shfl_xor(mx, 8));
        float zs = 0.f;
        #pragma unroll
        for (int jt = 0; jt < 8; ++jt) { s[jt] = __expf(s[jt] - mx); zs += s[jt]; }
        zs += __shfl_xor(zs, 1);
        zs += __shfl_xor(zs, 2);
        zs += __shfl_xor(zs, 4);
        zs += __shfl_xor(zs, 8);
        if (lc == 0) zin[r] = 1.f / zs;
        #pragma unroll
        for (int jt = 0; jt < 8; ++jt) {
            const unsigned short hh = bf16h(s[jt]);
            Ph[r * 136 + jt * 16 + lc] = hh;
            Pl[r * 136 + jt * 16 + lc] = bf16h(s[jt] - bf16f(hh));
        }
    }
    #pragma unroll
    for (int it = 0; it < 2; ++it) {           // Vt chunk 0: 64 hd x 8 chunks
        const int task = it * 256 + t;
        const int hd = task >> 3, jc = (task & 7) * 8;
        const size_t g0 = ((size_t)(b * 16 + h) * 64 + hd) * 128 + jc;
        *(int4*)&Vth[hd * 72 + jc] = *(const int4*)(VtHi + g0);
        *(int4*)&Vtl[hd * 72 + jc] = *(const int4*)(VtLo + g0);
    }
    __syncthreads();

    // ---- phase 3: PV chunk 0 ----
    f32x4 oacc[4];
    #pragma unroll
    for (int nt = 0; nt < 4; ++nt) oacc[nt] = (f32x4){0.f, 0.f, 0.f, 0.f};
    #pragma unroll
    for (int ks = 0; ks < 2; ++ks) {
        const bf16x8 a_h = *(bf16x8*)&Ph[(r0w + lc) * 136 + ks * 32 + lg * 8];
        const bf16x8 a_l = *(bf16x8*)&Pl[(r0w + lc) * 136 + ks * 32 + lg * 8];
        #pragma unroll
        for (int nt = 0; nt < 4; ++nt) {
            const bf16x8 b_h = *(bf16x8*)&Vth[(nt * 16 + lc) * 72 + ks * 32 + lg * 8];
            const bf16x8 b_l = *(bf16x8*)&Vtl[(nt * 16 + lc) * 72 + ks * 32 + lg * 8];
            oacc[nt] = __builtin_amdgcn_mfma_f32_16x16x32_bf16(a_h, b_h, oacc[nt], 0, 0, 0);
            oacc[nt] = __builtin_amdgcn_mfma_f32_16x16x32_bf16(a_l, b_h, oacc[nt], 0, 0, 0);
            oacc[nt] = __builtin_amdgcn_mfma_f32_16x16x32_bf16(a_h, b_l, oacc[nt], 0, 0, 0);
        }
    }
    __syncthreads();

    // ---- phase 4: stage Vt chunk 1 ----
    #pragma unroll
    for (int it = 0; it < 2; ++it) {
        const int task = it * 256 + t;
        const int hd = task >> 3, jc = (task & 7) * 8;
        const size_t g0 = ((size_t)(b * 16 + h) * 64 + hd) * 128 + 64 + jc;
        *(int4*)&Vth[hd * 72 + jc] = *(const int4*)(VtHi + g0);
        *(int4*)&Vtl[hd * 72 + jc] = *(const int4*)(VtLo + g0);
    }
    __syncthreads();

    // ---- phase 5: PV chunk 1 + epilogue ----
    #pragma unroll
    for (int ks = 0; ks < 2; ++ks) {
        const bf16x8 a_h = *(bf16x8*)&Ph[(r0w + lc) * 136 + 64 + ks * 32 + lg * 8];
        const bf16x8 a_l = *(bf16x8*)&Pl[(r0w + lc) * 136 + 64 + ks * 32 + lg * 8];
        #pragma unroll
        for (int nt = 0; nt < 4; ++nt) {
            const bf16x8 b_h = *(bf16x8*)&Vth[(nt * 16 + lc) * 72 + ks * 32 + lg * 8];
            const bf16x8 b_l = *(bf16x8*)&Vtl[(nt * 16 + lc) * 72 + ks * 32 + lg * 8];
            oacc[nt] = __builtin_amdgcn_mfma_f32_16x16x32_bf16(a_h, b_h, oacc[nt], 0, 0, 0);
            oacc[nt] = __builtin_amdgcn_mfma_f32_16x16x32_bf16(a_l, b_h, oacc[nt], 0, 0, 0);
            oacc[nt] = __builtin_amdgcn_mfma_f32_16x16x32_bf16(a_h, b_l, oacc[nt], 0, 0, 0);
        }
    }
    #pragma unroll
    for (int nt = 0; nt < 4; ++nt)
        #pragma unroll
        for (int q = 0; q < 4; ++q) {
            const int r = r0w + lg * 4 + q;
            const float val = oacc[nt][q] * zin[r];
            const int i_glob = ihalf * 64 + r;
            const size_t oa = (size_t)(i_glob * 8 + b) * 1024 + h * 64 + nt * 16 + lc;
            const unsigned short hh = bf16h(val);
            Ahi[oa] = hh;
            Alo[oa] = bf16h(val - bf16f(hh));
        }
}

// ---------------------------------------------------------------------------
extern "C" void kernel_launch(void* const* d_in, const int* in_sizes, int n_in,
                              void* d_out, int out_size, void* d_ws, size_t ws_size,
                              hipStream_t stream) {
    (void)in_sizes; (void)n_in; (void)out_size; (void)ws_size;
    const float* query   = (const float*)d_in[0];
    const float* rel_pe  = (const float*)d_in[1];
    const float* Wq      = (const float*)d_in[3];
    const float* Wk      = (const float*)d_in[4];
    const float* Wv      = (const float*)d_in[5];
    const float* Wr      = (const float*)d_in[6];
    const float* Wo      = (const float*)d_in[7];
    const float* spk_emb = (const float*)d_in[8];
    const int*   SM      = (const int*)d_in[10];
    float* out = (float*)d_out;

    const size_t MB1 = 1u << 20;
    ushort_t* us = (ushort_t*)d_ws;
    ushort_t* qhi  = us + 0 * MB1;   ushort_t* qlo  = us + 1 * MB1;
    ushort_t* wqhi = us + 2 * MB1;   ushort_t* wqlo = us + 3 * MB1;
    ushort_t* wkhi = us + 4 * MB1;   ushort_t* wklo = us + 5 * MB1;
    ushort_t* wvhi = us + 6 * MB1;   ushort_t* wvlo = us + 7 * MB1;
    ushort_t* wohi = us + 8 * MB1;   ushort_t* wolo = us + 9 * MB1;
    ushort_t* nqhi = us + 10 * MB1;  ushort_t* nqlo = us + 11 * MB1;
    ushort_t* khi  = us + 12 * MB1;  ushort_t* klo  = us + 13 * MB1;
    ushort_t* vhi  = us + 14 * MB1;  ushort_t* vlo  = us + 15 * MB1;
    float* WSE = (float*)(us + 16 * MB1);
    float* Gp  = WSE + 16384;
    ushort_t* atthi = qhi;   // query dead after QKV gemm
    ushort_t* attlo = qlo;
    ushort_t* vthi  = wqhi;  // Wq dead after QKV gemm
    ushort_t* vtlo  = wqlo;

    convert5_kernel<<<dim3(512, 1, 5), 256, 0, stream>>>(
        query, Wq, Wk, Wv, Wo,
        qhi, qlo, wqhi, wqlo, wkhi, wklo, wvhi, wvlo, wohi, wolo);

    gemm4_kernel<<<dim3(8, 8, 3), 512, 0, stream>>>(
        qhi, qlo, wqhi, wqlo, wkhi, wklo, wvhi, wvlo,
        nqhi, nqlo, khi, klo, vhi, vlo, nullptr, spk_emb, 0);

    transposeV_kernel<<<dim3(128, 2), 256, 0, stream>>>(vhi, vlo, vthi, vtlo);
    wse_kernel<<<64, 256, 0, stream>>>(Wr, spk_emb, WSE);
    g_kernel<<<1024, 256, 0, stream>>>(rel_pe, WSE, Gp);

    attn3_kernel<<<256, 256, 0, stream>>>(
        nqhi, nqlo, khi, klo, vthi, vtlo, Gp, SM, spk_emb, atthi, attlo);

    gemm4_kernel<<<dim3(8, 8, 1), 512, 0, stream>>>(
        atthi, attlo, wohi, wolo, wohi, wolo, wohi, wolo,
        nullptr, nullptr, nullptr, nullptr, nullptr, nullptr,
        out, nullptr, 1);
}

// Round 8
// 188.642 us; speedup vs baseline: 1.0628x; 1.0628x over previous
//
#include <hip/hip_runtime.h>

#define Dm 1024
#define Lq 128
#define Bq 8
#define Hh 16
#define HDim 64

typedef __attribute__((ext_vector_type(8))) short bf16x8;
typedef __attribute__((ext_vector_type(4))) float f32x4;
typedef unsigned short ushort_t;

#define GLOAD16(gp, lp) __builtin_amdgcn_global_load_lds( \
    (const __attribute__((address_space(1))) void*)(gp), \
    (__attribute__((address_space(3))) void*)(lp), 16, 0, 0)

__device__ __forceinline__ unsigned short bf16h(float x) {
    unsigned u = __float_as_uint(x);
    return (unsigned short)((u + 0x7FFFu + ((u >> 16) & 1u)) >> 16);
}
__device__ __forceinline__ float bf16f(unsigned short s) {
    return __uint_as_float(((unsigned)s) << 16);
}

// ---------------------------------------------------------------------------
// convert5: fp32 -> (bf16 hi, bf16 lo) for {query, Wq, Wk, Wv, Wo} (1M each)
// ---------------------------------------------------------------------------
__global__ __launch_bounds__(256) void convert5_kernel(
    const float* __restrict__ s0, const float* __restrict__ s1, const float* __restrict__ s2,
    const float* __restrict__ s3, const float* __restrict__ s4,
    ushort_t* __restrict__ d0h, ushort_t* __restrict__ d0l,
    ushort_t* __restrict__ d1h, ushort_t* __restrict__ d1l,
    ushort_t* __restrict__ d2h, ushort_t* __restrict__ d2l,
    ushort_t* __restrict__ d3h, ushort_t* __restrict__ d3l,
    ushort_t* __restrict__ d4h, ushort_t* __restrict__ d4l)
{
    const int z = blockIdx.z;
    const float* src = (z == 0) ? s0 : (z == 1) ? s1 : (z == 2) ? s2 : (z == 3) ? s3 : s4;
    ushort_t* dh = (z == 0) ? d0h : (z == 1) ? d1h : (z == 2) ? d2h : (z == 3) ? d3h : d4h;
    ushort_t* dl = (z == 0) ? d0l : (z == 1) ? d1l : (z == 2) ? d2l : (z == 3) ? d3l : d4l;
    const int idx = (blockIdx.x * 256 + threadIdx.x) * 8;
    const float4 a = *(const float4*)(src + idx);
    const float4 b = *(const float4*)(src + idx + 4);
    float xs[8] = {a.x, a.y, a.z, a.w, b.x, b.y, b.z, b.w};
    unsigned hp[4], lp[4];
    #pragma unroll
    for (int e = 0; e < 4; ++e) {
        unsigned short h0 = bf16h(xs[2*e]), h1 = bf16h(xs[2*e+1]);
        unsigned short l0 = bf16h(xs[2*e]   - bf16f(h0));
        unsigned short l1 = bf16h(xs[2*e+1] - bf16f(h1));
        hp[e] = (unsigned)h0 | ((unsigned)h1 << 16);
        lp[e] = (unsigned)l0 | ((unsigned)l1 << 16);
    }
    *(int4*)(dh + idx) = *(int4*)hp;
    *(int4*)(dl + idx) = *(int4*)lp;
}

// ---------------------------------------------------------------------------
// gemm5: OUT[r,c] = sum_k X[r,k]*W[c,k] via bf16 hi/lo 3-pass MFMA.
// 64x64 tile (grid: 16x16xZ -> 768/256 blocks, 3/1 per CU), 4 waves (2x2 of
// 32x32), BK=32, DOUBLE-buffered LDS staged by global_load_lds width=16.
// One barrier per K-step: issue gload(next) -> compute(cur) -> barrier
// (vmcnt drain lands after compute, loads hide under the 12 MFMAs).
// mode 0: bf16 hi/lo outputs (z selects W/O; bias on z==0). mode 1: fp32.
// ---------------------------------------------------------------------------
__global__ __launch_bounds__(256) void gemm5_kernel(
    const ushort_t* __restrict__ Xhi, const ushort_t* __restrict__ Xlo,
    const ushort_t* __restrict__ W0h, const ushort_t* __restrict__ W0l,
    const ushort_t* __restrict__ W1h, const ushort_t* __restrict__ W1l,
    const ushort_t* __restrict__ W2h, const ushort_t* __restrict__ W2l,
    ushort_t* __restrict__ O0h, ushort_t* __restrict__ O0l,
    ushort_t* __restrict__ O1h, ushort_t* __restrict__ O1l,
    ushort_t* __restrict__ O2h, ushort_t* __restrict__ O2l,
    float* __restrict__ Ofp, const float* __restrict__ bias, int mode)
{
    const int z = blockIdx.z;
    const ushort_t* Wh = (z == 0) ? W0h : (z == 1) ? W1h : W2h;
    const ushort_t* Wl = (z == 0) ? W0l : (z == 1) ? W1l : W2l;
    ushort_t* Ohi = (z == 0) ? O0h : (z == 1) ? O1h : O2h;
    ushort_t* Olo = (z == 0) ? O0l : (z == 1) ? O1l : O2l;

    __shared__ __align__(16) ushort_t Ah[2][64 * 32];   // 32 KB total (dbuf)
    __shared__ __align__(16) ushort_t Al[2][64 * 32];
    __shared__ __align__(16) ushort_t Bh[2][64 * 32];
    __shared__ __align__(16) ushort_t Bl[2][64 * 32];

    const int t = threadIdx.x, w = t >> 6, l = t & 63;
    const int r0 = blockIdx.y * 64, c0 = blockIdx.x * 64;
    const int wr = w >> 1, wc = w & 1;              // 2x2 waves of 32x32
    const int lc = l & 15, lg = l >> 4, lk = lg * 8;

    // staging: thread t <-> row t>>2, 16B-chunk t&3 (LDS dest linear in t)
    const size_t xg = (size_t)(r0 + (t >> 2)) * Dm + (t & 3) * 8;
    const size_t wg = (size_t)(c0 + (t >> 2)) * Dm + (t & 3) * 8;

    f32x4 acc[2][2];
    #pragma unroll
    for (int m = 0; m < 2; ++m)
        #pragma unroll
        for (int n = 0; n < 2; ++n)
            acc[m][n] = (f32x4){0.f, 0.f, 0.f, 0.f};

    // prologue: stage K-step 0 into buf 0
    GLOAD16(Xhi + xg, &Ah[0][t * 8]);
    GLOAD16(Xlo + xg, &Al[0][t * 8]);
    GLOAD16(Wh + wg,  &Bh[0][t * 8]);
    GLOAD16(Wl + wg,  &Bl[0][t * 8]);
    __syncthreads();

    int cur = 0;
    for (int step = 0; step < 32; ++step) {
        const bool more = (step < 31);
        if (more) {
            const int kt = (step + 1) * 32;
            const int nb = cur ^ 1;
            GLOAD16(Xhi + xg + kt, &Ah[nb][t * 8]);
            GLOAD16(Xlo + xg + kt, &Al[nb][t * 8]);
            GLOAD16(Wh + wg + kt,  &Bh[nb][t * 8]);
            GLOAD16(Wl + wg + kt,  &Bl[nb][t * 8]);
        }
        bf16x8 a_h[2], a_l[2], b_h[2], b_l[2];
        #pragma unroll
        for (int m = 0; m < 2; ++m) {
            const int row = wr * 32 + m * 16 + lc;
            a_h[m] = *(bf16x8*)&Ah[cur][row * 32 + lk];
            a_l[m] = *(bf16x8*)&Al[cur][row * 32 + lk];
        }
        #pragma unroll
        for (int n = 0; n < 2; ++n) {
            const int col = wc * 32 + n * 16 + lc;
            b_h[n] = *(bf16x8*)&Bh[cur][col * 32 + lk];
            b_l[n] = *(bf16x8*)&Bl[cur][col * 32 + lk];
        }
        #pragma unroll
        for (int m = 0; m < 2; ++m)
            #pragma unroll
            for (int n = 0; n < 2; ++n) {
                acc[m][n] = __builtin_amdgcn_mfma_f32_16x16x32_bf16(a_h[m], b_h[n], acc[m][n], 0, 0, 0);
                acc[m][n] = __builtin_amdgcn_mfma_f32_16x16x32_bf16(a_l[m], b_h[n], acc[m][n], 0, 0, 0);
                acc[m][n] = __builtin_amdgcn_mfma_f32_16x16x32_bf16(a_h[m], b_l[n], acc[m][n], 0, 0, 0);
            }
        __syncthreads();   // drains the next-buf loads AFTER compute; guards cur reuse
        cur ^= 1;
    }

    float bz[2] = {0.f, 0.f};
    if (mode == 0 && z == 0 && bias != nullptr) {
        #pragma unroll
        for (int n = 0; n < 2; ++n)
            bz[n] = bias[c0 + wc * 32 + n * 16 + lc];
    }
    #pragma unroll
    for (int m = 0; m < 2; ++m)
        #pragma unroll
        for (int n = 0; n < 2; ++n)
            #pragma unroll
            for (int q = 0; q < 4; ++q) {
                const int r = r0 + wr * 32 + m * 16 + lg * 4 + q;
                const int c = c0 + wc * 32 + n * 16 + lc;
                float v = acc[m][n][q] + bz[n];
                const size_t oa = (size_t)r * Dm + c;
                if (mode == 1) {
                    Ofp[oa] = v;
                } else {
                    const unsigned short hh = bf16h(v);
                    Ohi[oa] = hh;
                    Olo[oa] = bf16h(v - bf16f(hh));
                }
            }
}

// ---------------------------------------------------------------------------
// wse[h,k] = sum_hd Wr[h*64+hd, k] * spk_emb[0, h*64+hd]    (16 x 1024), fp32
// ---------------------------------------------------------------------------
__global__ __launch_bounds__(256) void wse_kernel(
    const float* __restrict__ Wr, const float* __restrict__ spk_emb,
    float* __restrict__ WSE)
{
    __shared__ float se[64];
    const int t = threadIdx.x;
    const int h = blockIdx.x >> 2;
    const int k = (blockIdx.x & 3) * 256 + t;
    if (t < 64) se[t] = spk_emb[h * 64 + t];
    __syncthreads();
    float s = 0.f;
    #pragma unroll 8
    for (int hd = 0; hd < 64; ++hd)
        s += Wr[(h * 64 + hd) * Dm + k] * se[hd];
    WSE[h * Dm + k] = s;
}

// ---------------------------------------------------------------------------
// g[p, h] = sum_k rel_pe[p, k] * wse[h, k]    (1024 x 16), fp32
// ---------------------------------------------------------------------------
__global__ __launch_bounds__(256) void g_kernel(
    const float* __restrict__ rel_pe, const float* __restrict__ WSE,
    float* __restrict__ G)
{
    __shared__ float rp[1024];
    const int t = threadIdx.x;
    const int p = blockIdx.x;
    ((float4*)rp)[t] = ((const float4*)(rel_pe + p * Dm))[t];
    __syncthreads();
    const int h = t >> 4, part = t & 15;
    float s = 0.f;
    #pragma unroll 8
    for (int m = 0; m < 64; ++m) {
        const int kk = part + (m << 4);
        s += rp[kk] * WSE[h * Dm + kk];
    }
    s += __shfl_down(s, 8, 16);
    s += __shfl_down(s, 4, 16);
    s += __shfl_down(s, 2, 16);
    s += __shfl_down(s, 1, 16);
    if (part == 0) G[p * 16 + h] = s;
}

// ---------------------------------------------------------------------------
// transposeV: per (b,h) slice, V [j=128][hd=64] -> Vt [hd=64][j=128]
// (hi/lo selected by blockIdx.y). Coalesced both sides via LDS tile.
// ---------------------------------------------------------------------------
__global__ __launch_bounds__(256) void transposeV_kernel(
    const ushort_t* __restrict__ Vhi, const ushort_t* __restrict__ Vlo,
    ushort_t* __restrict__ VtHi, ushort_t* __restrict__ VtLo)
{
    __shared__ __align__(16) ushort_t T[128 * 72];
    const int blk = blockIdx.x;
    const int b = blk >> 4, h = blk & 15;
    const ushort_t* src = blockIdx.y ? Vlo : Vhi;
    ushort_t* dst = blockIdx.y ? VtLo : VtHi;
    const int t = threadIdx.x;
    #pragma unroll
    for (int it = 0; it < 4; ++it) {
        const int task = it * 256 + t;
        const int j = task >> 3, hc = (task & 7) * 8;
        *(int4*)&T[j * 72 + hc] = *(const int4*)(src + (size_t)(j * 8 + b) * 1024 + h * 64 + hc);
    }
    __syncthreads();
    #pragma unroll
    for (int it = 0; it < 4; ++it) {
        const int task = it * 256 + t;
        const int hd = task >> 4, jc = (task & 15) * 8;
        ushort_t tmp[8];
        #pragma unroll
        for (int e = 0; e < 8; ++e) tmp[e] = T[(jc + e) * 72 + hd];
        *(int4*)(dst + ((size_t)(b * 16 + h) * 64 + hd) * 128 + jc) = *(int4*)tmp;
    }
}

// ---------------------------------------------------------------------------
// attn3: MFMA attention. Block = (b,h,ihalf): 64 q-rows x 128 kv. 4 waves,
// each wave a 16-row strip. QK^T and PV via 16x16x32 bf16 MFMA hi/lo 3-pass;
// softmax on accumulator fragments (row = 16 lanes x 8 tiles). (validated r6)
// ---------------------------------------------------------------------------
__global__ __launch_bounds__(256) void attn3_kernel(
    const ushort_t* __restrict__ NQhi, const ushort_t* __restrict__ NQlo,
    const ushort_t* __restrict__ Khi,  const ushort_t* __restrict__ Klo,
    const ushort_t* __restrict__ VtHi, const ushort_t* __restrict__ VtLo,
    const float* __restrict__ G, const int* __restrict__ SM,
    const float* __restrict__ spk_emb,
    ushort_t* __restrict__ Ahi, ushort_t* __restrict__ Alo)
{
    __shared__ __align__(16) ushort_t KP[18432];  // Kh|Kl, later Ph|Pl
    __shared__ __align__(16) ushort_t QV[9216];   // Qh|Ql, later Vth|Vtl
    __shared__ float cp[128];
    __shared__ float Es[128];      // E[r][m] = Es[r*2+m]
    __shared__ float se[128];
    __shared__ float zin[64];
    __shared__ unsigned SMw[256];  // [r][word]

    const int blk = blockIdx.x, n = blk >> 1, ihalf = blk & 1;
    const int b = n >> 4, h = n & 15;
    const int t = threadIdx.x, w = t >> 6, l = t & 63;
    const int lc = l & 15, lg = l >> 4;
    const int r0w = w * 16;

    ushort_t* Kh = KP;            ushort_t* Kl = KP + 9216;
    ushort_t* Qh = QV;            ushort_t* Ql = QV + 4608;

    // ---- phase 0: staging ----
    #pragma unroll
    for (int it = 0; it < 2; ++it) {           // Q: 64 rows x 8 chunks
        const int task = it * 256 + t;
        const int r = task >> 3, col = (task & 7) * 8;
        const size_t g0 = (size_t)((ihalf * 64 + r) * 8 + b) * 1024 + h * 64 + col;
        *(int4*)&Qh[r * 72 + col] = *(const int4*)(NQhi + g0);
        *(int4*)&Ql[r * 72 + col] = *(const int4*)(NQlo + g0);
    }
    #pragma unroll
    for (int it = 0; it < 4; ++it) {           // K: 128 rows x 8 chunks
        const int task = it * 256 + t;
        const int j = task >> 3, col = (task & 7) * 8;
        const size_t g0 = (size_t)(j * 8 + b) * 1024 + h * 64 + col;
        *(int4*)&Kh[j * 72 + col] = *(const int4*)(Khi + g0);
        *(int4*)&Kl[j * 72 + col] = *(const int4*)(Klo + g0);
    }
    {   // spk-mask bit pack: r = t>>2, word = t&3
        const int r = t >> 2, wd = t & 3;
        const int i_glob = ihalf * 64 + r;
        const int* sp = SM + ((size_t)b * 128 + i_glob) * 128 + wd * 32;
        unsigned bits = 0;
        #pragma unroll
        for (int e8 = 0; e8 < 8; ++e8) {
            const int4 v = *(const int4*)(sp + e8 * 4);
            bits |= (v.x != 0 ? 1u : 0u) << (e8 * 4 + 0);
            bits |= (v.y != 0 ? 1u : 0u) << (e8 * 4 + 1);
            bits |= (v.z != 0 ? 1u : 0u) << (e8 * 4 + 2);
            bits |= (v.w != 0 ? 1u : 0u) << (e8 * 4 + 3);
        }
        SMw[r * 4 + wd] = bits;
    }
    if (t < 128) {
        cp[t] = G[((((t >> 4) << 7) + ((t & 15) << 3) + b) << 4) + h];
        se[t] = spk_emb[(t >> 6) * 1024 + h * 64 + (t & 63)];
    }
    __syncthreads();

    // ---- phase 1: QK^T MFMA + speaker dots E ----
    f32x4 acc[8];
    #pragma unroll
    for (int jt = 0; jt < 8; ++jt) acc[jt] = (f32x4){0.f, 0.f, 0.f, 0.f};
    #pragma unroll
    for (int ks = 0; ks < 2; ++ks) {
        const bf16x8 a_h = *(bf16x8*)&Qh[(r0w + lc) * 72 + ks * 32 + lg * 8];
        const bf16x8 a_l = *(bf16x8*)&Ql[(r0w + lc) * 72 + ks * 32 + lg * 8];
        #pragma unroll
        for (int jt = 0; jt < 8; ++jt) {
            const bf16x8 b_h = *(bf16x8*)&Kh[(jt * 16 + lc) * 72 + ks * 32 + lg * 8];
            const bf16x8 b_l = *(bf16x8*)&Kl[(jt * 16 + lc) * 72 + ks * 32 + lg * 8];
            acc[jt] = __builtin_amdgcn_mfma_f32_16x16x32_bf16(a_h, b_h, acc[jt], 0, 0, 0);
            acc[jt] = __builtin_amdgcn_mfma_f32_16x16x32_bf16(a_l, b_h, acc[jt], 0, 0, 0);
            acc[jt] = __builtin_amdgcn_mfma_f32_16x16x32_bf16(a_h, b_l, acc[jt], 0, 0, 0);
        }
    }
    {   // E[r][m] = new_q[r] . spk_emb[m] (per-head slice)
        const int r = t >> 2, m = (t >> 1) & 1, half = t & 1;
        float v = 0.f;
        #pragma unroll
        for (int e = 0; e < 32; ++e) {
            const int hd = half * 32 + e;
            const float qf = bf16f(Qh[r * 72 + hd]) + bf16f(Ql[r * 72 + hd]);
            v += qf * se[m * 64 + hd];
        }
        v += __shfl_xor(v, 1);
        if (half == 0) Es[r * 2 + m] = v;
    }
    __syncthreads();

    // ---- phase 2: softmax in fragments; write P hi/lo; stage Vt chunk 0 ----
    ushort_t* Ph = KP;            ushort_t* Pl = KP + 8704;
    ushort_t* Vth = QV;           ushort_t* Vtl = QV + 4608;
    #pragma unroll
    for (int q = 0; q < 4; ++q) {
        const int r = r0w + lg * 4 + q;
        const int i_glob = ihalf * 64 + r;
        const float e0 = Es[r * 2 + 0], e1 = Es[r * 2 + 1];
        float s[8];
        #pragma unroll
        for (int jt = 0; jt < 8; ++jt) {
            const int j = jt * 16 + lc;
            if (j > i_glob) {
                s[jt] = 1e-30f;
            } else {
                const unsigned bit = (SMw[r * 4 + (jt >> 1)] >> ((jt & 1) * 16 + lc)) & 1u;
                s[jt] = (acc[jt][q] + (bit ? e1 : e0) + cp[127 + j - i_glob]) * 0.125f;
            }
        }
        float mx = s[0];
        #pragma unroll
        for (int jt = 1; jt < 8; ++jt) mx = fmaxf(mx, s[jt]);
        mx = fmaxf(mx, __shfl_xor(mx, 1));
        mx = fmaxf(mx, __shfl_xor(mx, 2));
        mx = fmaxf(mx, __shfl_xor(mx, 4));
        mx = fmaxf(mx, __shfl_xor(mx, 8));
        float zs = 0.f;
        #pragma unroll
        for (int jt = 0; jt < 8; ++jt) { s[jt] = __expf(s[jt] - mx); zs += s[jt]; }
        zs += __shfl_xor(zs, 1);
        zs += __shfl_xor(zs, 2);
        zs += __shfl_xor(zs, 4);
        zs += __shfl_xor(zs, 8);
        if (lc == 0) zin[r] = 1.f / zs;
        #pragma unroll
        for (int jt = 0; jt < 8; ++jt) {
            const unsigned short hh = bf16h(s[jt]);
            Ph[r * 136 + jt * 16 + lc] = hh;
            Pl[r * 136 + jt * 16 + lc] = bf16h(s[jt] - bf16f(hh));
        }
    }
    #pragma unroll
    for (int it = 0; it < 2; ++it) {           // Vt chunk 0: 64 hd x 8 chunks
        const int task = it * 256 + t;
        const int hd = task >> 3, jc = (task & 7) * 8;
        const size_t g0 = ((size_t)(b * 16 + h) * 64 + hd) * 128 + jc;
        *(int4*)&Vth[hd * 72 + jc] = *(const int4*)(VtHi + g0);
        *(int4*)&Vtl[hd * 72 + jc] = *(const int4*)(VtLo + g0);
    }
    __syncthreads();

    // ---- phase 3: PV chunk 0 ----
    f32x4 oacc[4];
    #pragma unroll
    for (int nt = 0; nt < 4; ++nt) oacc[nt] = (f32x4){0.f, 0.f, 0.f, 0.f};
    #pragma unroll
    for (int ks = 0; ks < 2; ++ks) {
        const bf16x8 a_h = *(bf16x8*)&Ph[(r0w + lc) * 136 + ks * 32 + lg * 8];
        const bf16x8 a_l = *(bf16x8*)&Pl[(r0w + lc) * 136 + ks * 32 + lg * 8];
        #pragma unroll
        for (int nt = 0; nt < 4; ++nt) {
            const bf16x8 b_h = *(bf16x8*)&Vth[(nt * 16 + lc) * 72 + ks * 32 + lg * 8];
            const bf16x8 b_l = *(bf16x8*)&Vtl[(nt * 16 + lc) * 72 + ks * 32 + lg * 8];
            oacc[nt] = __builtin_amdgcn_mfma_f32_16x16x32_bf16(a_h, b_h, oacc[nt], 0, 0, 0);
            oacc[nt] = __builtin_amdgcn_mfma_f32_16x16x32_bf16(a_l, b_h, oacc[nt], 0, 0, 0);
            oacc[nt] = __builtin_amdgcn_mfma_f32_16x16x32_bf16(a_h, b_l, oacc[nt], 0, 0, 0);
        }
    }
    __syncthreads();

    // ---- phase 4: stage Vt chunk 1 ----
    #pragma unroll
    for (int it = 0; it < 2; ++it) {
        const int task = it * 256 + t;
        const int hd = task >> 3, jc = (task & 7) * 8;
        const size_t g0 = ((size_t)(b * 16 + h) * 64 + hd) * 128 + 64 + jc;
        *(int4*)&Vth[hd * 72 + jc] = *(const int4*)(VtHi + g0);
        *(int4*)&Vtl[hd * 72 + jc] = *(const int4*)(VtLo + g0);
    }
    __syncthreads();

    // ---- phase 5: PV chunk 1 + epilogue ----
    #pragma unroll
    for (int ks = 0; ks < 2; ++ks) {
        const bf16x8 a_h = *(bf16x8*)&Ph[(r0w + lc) * 136 + 64 + ks * 32 + lg * 8];
        const bf16x8 a_l = *(bf16x8*)&Pl[(r0w + lc) * 136 + 64 + ks * 32 + lg * 8];
        #pragma unroll
        for (int nt = 0; nt < 4; ++nt) {
            const bf16x8 b_h = *(bf16x8*)&Vth[(nt * 16 + lc) * 72 + ks * 32 + lg * 8];
            const bf16x8 b_l = *(bf16x8*)&Vtl[(nt * 16 + lc) * 72 + ks * 32 + lg * 8];
            oacc[nt] = __builtin_amdgcn_mfma_f32_16x16x32_bf16(a_h, b_h, oacc[nt], 0, 0, 0);
            oacc[nt] = __builtin_amdgcn_mfma_f32_16x16x32_bf16(a_l, b_h, oacc[nt], 0, 0, 0);
            oacc[nt] = __builtin_amdgcn_mfma_f32_16x16x32_bf16(a_h, b_l, oacc[nt], 0, 0, 0);
        }
    }
    #pragma unroll
    for (int nt = 0; nt < 4; ++nt)
        #pragma unroll
        for (int q = 0; q < 4; ++q) {
            const int r = r0w + lg * 4 + q;
            const float val = oacc[nt][q] * zin[r];
            const int i_glob = ihalf * 64 + r;
            const size_t oa = (size_t)(i_glob * 8 + b) * 1024 + h * 64 + nt * 16 + lc;
            const unsigned short hh = bf16h(val);
            Ahi[oa] = hh;
            Alo[oa] = bf16h(val - bf16f(hh));
        }
}

// ---------------------------------------------------------------------------
extern "C" void kernel_launch(void* const* d_in, const int* in_sizes, int n_in,
                              void* d_out, int out_size, void* d_ws, size_t ws_size,
                              hipStream_t stream) {
    (void)in_sizes; (void)n_in; (void)out_size; (void)ws_size;
    const float* query   = (const float*)d_in[0];
    const float* rel_pe  = (const float*)d_in[1];
    const float* Wq      = (const float*)d_in[3];
    const float* Wk      = (const float*)d_in[4];
    const float* Wv      = (const float*)d_in[5];
    const float* Wr      = (const float*)d_in[6];
    const float* Wo      = (const float*)d_in[7];
    const float* spk_emb = (const float*)d_in[8];
    const int*   SM      = (const int*)d_in[10];
    float* out = (float*)d_out;

    const size_t MB1 = 1u << 20;
    ushort_t* us = (ushort_t*)d_ws;
    ushort_t* qhi  = us + 0 * MB1;   ushort_t* qlo  = us + 1 * MB1;
    ushort_t* wqhi = us + 2 * MB1;   ushort_t* wqlo = us + 3 * MB1;
    ushort_t* wkhi = us + 4 * MB1;   ushort_t* wklo = us + 5 * MB1;
    ushort_t* wvhi = us + 6 * MB1;   ushort_t* wvlo = us + 7 * MB1;
    ushort_t* wohi = us + 8 * MB1;   ushort_t* wolo = us + 9 * MB1;
    ushort_t* nqhi = us + 10 * MB1;  ushort_t* nqlo = us + 11 * MB1;
    ushort_t* khi  = us + 12 * MB1;  ushort_t* klo  = us + 13 * MB1;
    ushort_t* vhi  = us + 14 * MB1;  ushort_t* vlo  = us + 15 * MB1;
    float* WSE = (float*)(us + 16 * MB1);
    float* Gp  = WSE + 16384;
    ushort_t* atthi = qhi;   // query dead after QKV gemm
    ushort_t* attlo = qlo;
    ushort_t* vthi  = wqhi;  // Wq dead after QKV gemm
    ushort_t* vtlo  = wqlo;

    convert5_kernel<<<dim3(512, 1, 5), 256, 0, stream>>>(
        query, Wq, Wk, Wv, Wo,
        qhi, qlo, wqhi, wqlo, wkhi, wklo, wvhi, wvlo, wohi, wolo);

    gemm5_kernel<<<dim3(16, 16, 3), 256, 0, stream>>>(
        qhi, qlo, wqhi, wqlo, wkhi, wklo, wvhi, wvlo,
        nqhi, nqlo, khi, klo, vhi, vlo, nullptr, spk_emb, 0);

    transposeV_kernel<<<dim3(128, 2), 256, 0, stream>>>(vhi, vlo, vthi, vtlo);
    wse_kernel<<<64, 256, 0, stream>>>(Wr, spk_emb, WSE);
    g_kernel<<<1024, 256, 0, stream>>>(rel_pe, WSE, Gp);

    attn3_kernel<<<256, 256, 0, stream>>>(
        nqhi, nqlo, khi, klo, vthi, vtlo, Gp, SM, spk_emb, atthi, attlo);

    gemm5_kernel<<<dim3(16, 16, 1), 256, 0, stream>>>(
        atthi, attlo, wohi, wolo, wohi, wolo, wohi, wolo,
        nullptr, nullptr, nullptr, nullptr, nullptr, nullptr,
        out, nullptr, 1);
}

// Round 9
// 168.219 us; speedup vs baseline: 1.1918x; 1.1214x over previous
//
#include <hip/hip_runtime.h>

#define Dm 1024
#define Lq 128
#define Bq 8
#define Hh 16
#define HDim 64

typedef __attribute__((ext_vector_type(8))) short bf16x8;
typedef __attribute__((ext_vector_type(4))) float f32x4;
typedef unsigned short ushort_t;

__device__ __forceinline__ unsigned short bf16h(float x) {
    unsigned u = __float_as_uint(x);
    return (unsigned short)((u + 0x7FFFu + ((u >> 16) & 1u)) >> 16);
}
__device__ __forceinline__ float bf16f(unsigned short s) {
    return __uint_as_float(((unsigned)s) << 16);
}

// ---------------------------------------------------------------------------
// convert6: z=0..4 -> fp32 to (bf16 hi, lo) for {query,Wq,Wk,Wv,Wo};
// z=5 (x<64) -> wse[h,k] = sum_hd Wr[h*64+hd,k] * spk_emb[0,h*64+hd]
// ---------------------------------------------------------------------------
__global__ __launch_bounds__(256) void convert6_kernel(
    const float* __restrict__ s0, const float* __restrict__ s1, const float* __restrict__ s2,
    const float* __restrict__ s3, const float* __restrict__ s4,
    ushort_t* __restrict__ d0h, ushort_t* __restrict__ d0l,
    ushort_t* __restrict__ d1h, ushort_t* __restrict__ d1l,
    ushort_t* __restrict__ d2h, ushort_t* __restrict__ d2l,
    ushort_t* __restrict__ d3h, ushort_t* __restrict__ d3l,
    ushort_t* __restrict__ d4h, ushort_t* __restrict__ d4l,
    const float* __restrict__ Wr, const float* __restrict__ spk_emb,
    float* __restrict__ WSE)
{
    const int z = blockIdx.z;
    const int t = threadIdx.x;
    if (z == 5) {
        if (blockIdx.x >= 64) return;
        __shared__ float se[64];
        const int h = blockIdx.x >> 2;
        const int k = (blockIdx.x & 3) * 256 + t;
        if (t < 64) se[t] = spk_emb[h * 64 + t];
        __syncthreads();
        float s = 0.f;
        #pragma unroll 8
        for (int hd = 0; hd < 64; ++hd)
            s += Wr[(h * 64 + hd) * Dm + k] * se[hd];
        WSE[h * Dm + k] = s;
        return;
    }
    const float* src = (z == 0) ? s0 : (z == 1) ? s1 : (z == 2) ? s2 : (z == 3) ? s3 : s4;
    ushort_t* dh = (z == 0) ? d0h : (z == 1) ? d1h : (z == 2) ? d2h : (z == 3) ? d3h : d4h;
    ushort_t* dl = (z == 0) ? d0l : (z == 1) ? d1l : (z == 2) ? d2l : (z == 3) ? d3l : d4l;
    const int idx = (blockIdx.x * 256 + t) * 8;
    const float4 a = *(const float4*)(src + idx);
    const float4 b = *(const float4*)(src + idx + 4);
    float xs[8] = {a.x, a.y, a.z, a.w, b.x, b.y, b.z, b.w};
    unsigned hp[4], lp[4];
    #pragma unroll
    for (int e = 0; e < 4; ++e) {
        unsigned short h0 = bf16h(xs[2*e]), h1 = bf16h(xs[2*e+1]);
        unsigned short l0 = bf16h(xs[2*e]   - bf16f(h0));
        unsigned short l1 = bf16h(xs[2*e+1] - bf16f(h1));
        hp[e] = (unsigned)h0 | ((unsigned)h1 << 16);
        lp[e] = (unsigned)l0 | ((unsigned)l1 << 16);
    }
    *(int4*)(dh + idx) = *(int4*)hp;
    *(int4*)(dl + idx) = *(int4*)lp;
}

// ---------------------------------------------------------------------------
// gemm3: OUT[r,c] = sum_k X[r,k]*W[c,k] via bf16 hi/lo 3-pass MFMA.
// 64x64 tile, 4 waves (2x2 of 32x32), BK=32, double-buffered reg-staged LDS.
// (byte-identical to round-6 validated best: 174.3 us total)
// ---------------------------------------------------------------------------
__global__ __launch_bounds__(256) void gemm3_kernel(
    const ushort_t* __restrict__ Xhi, const ushort_t* __restrict__ Xlo,
    const ushort_t* __restrict__ W0h, const ushort_t* __restrict__ W0l,
    const ushort_t* __restrict__ W1h, const ushort_t* __restrict__ W1l,
    const ushort_t* __restrict__ W2h, const ushort_t* __restrict__ W2l,
    ushort_t* __restrict__ O0h, ushort_t* __restrict__ O0l,
    ushort_t* __restrict__ O1h, ushort_t* __restrict__ O1l,
    ushort_t* __restrict__ O2h, ushort_t* __restrict__ O2l,
    float* __restrict__ Ofp, const float* __restrict__ bias, int mode)
{
    const int z = blockIdx.z;
    const ushort_t* Wh = (z == 0) ? W0h : (z == 1) ? W1h : W2h;
    const ushort_t* Wl = (z == 0) ? W0l : (z == 1) ? W1l : W2l;
    ushort_t* Ohi = (z == 0) ? O0h : (z == 1) ? O1h : O2h;
    ushort_t* Olo = (z == 0) ? O0l : (z == 1) ? O1l : O2l;

    __shared__ __align__(16) short Axh[2][64][32];
    __shared__ __align__(16) short Axl[2][64][32];
    __shared__ __align__(16) short Bwh[2][64][32];
    __shared__ __align__(16) short Bwl[2][64][32];

    const int t = threadIdx.x, w = t >> 6, l = t & 63;
    const int r0 = blockIdx.y * 64, c0 = blockIdx.x * 64;
    const int wr = w >> 1, wc = w & 1;
    const int srow = t >> 2, sk = (t & 3) * 8;
    const int lr = l & 15, lk = (l >> 4) * 8;

    const size_t xbase = (size_t)(r0 + srow) * Dm + sk;
    const size_t wbase = (size_t)(c0 + srow) * Dm + sk;

    f32x4 acc[2][2];
    #pragma unroll
    for (int m = 0; m < 2; ++m)
        #pragma unroll
        for (int n = 0; n < 2; ++n)
            acc[m][n] = (f32x4){0.f, 0.f, 0.f, 0.f};

    {
        int4 xh = *(const int4*)(Xhi + xbase);
        int4 xl = *(const int4*)(Xlo + xbase);
        int4 wh = *(const int4*)(Wh + wbase);
        int4 wv = *(const int4*)(Wl + wbase);
        *(int4*)&Axh[0][srow][sk] = xh;
        *(int4*)&Axl[0][srow][sk] = xl;
        *(int4*)&Bwh[0][srow][sk] = wh;
        *(int4*)&Bwl[0][srow][sk] = wv;
    }
    __syncthreads();

    int cur = 0;
    for (int step = 0; step < 32; ++step) {
        int4 nxh, nxl, nwh, nwl;
        const bool more = (step < 31);
        if (more) {
            const int kt = (step + 1) * 32;
            nxh = *(const int4*)(Xhi + xbase + kt);
            nxl = *(const int4*)(Xlo + xbase + kt);
            nwh = *(const int4*)(Wh + wbase + kt);
            nwl = *(const int4*)(Wl + wbase + kt);
        }
        bf16x8 ah[2], al[2], bh[2], bl[2];
        #pragma unroll
        for (int m = 0; m < 2; ++m) {
            ah[m] = *(bf16x8*)&Axh[cur][wr * 32 + m * 16 + lr][lk];
            al[m] = *(bf16x8*)&Axl[cur][wr * 32 + m * 16 + lr][lk];
        }
        #pragma unroll
        for (int n = 0; n < 2; ++n) {
            bh[n] = *(bf16x8*)&Bwh[cur][wc * 32 + n * 16 + lr][lk];
            bl[n] = *(bf16x8*)&Bwl[cur][wc * 32 + n * 16 + lr][lk];
        }
        #pragma unroll
        for (int m = 0; m < 2; ++m)
            #pragma unroll
            for (int n = 0; n < 2; ++n) {
                acc[m][n] = __builtin_amdgcn_mfma_f32_16x16x32_bf16(ah[m], bh[n], acc[m][n], 0, 0, 0);
                acc[m][n] = __builtin_amdgcn_mfma_f32_16x16x32_bf16(al[m], bh[n], acc[m][n], 0, 0, 0);
                acc[m][n] = __builtin_amdgcn_mfma_f32_16x16x32_bf16(ah[m], bl[n], acc[m][n], 0, 0, 0);
            }
        if (more) {
            const int nb = cur ^ 1;
            *(int4*)&Axh[nb][srow][sk] = nxh;
            *(int4*)&Axl[nb][srow][sk] = nxl;
            *(int4*)&Bwh[nb][srow][sk] = nwh;
            *(int4*)&Bwl[nb][srow][sk] = nwl;
        }
        __syncthreads();
        cur ^= 1;
    }

    float bz[2] = {0.f, 0.f};
    if (mode == 0 && z == 0 && bias != nullptr) {
        #pragma unroll
        for (int n = 0; n < 2; ++n)
            bz[n] = bias[c0 + wc * 32 + n * 16 + lr];
    }
    #pragma unroll
    for (int m = 0; m < 2; ++m)
        #pragma unroll
        for (int n = 0; n < 2; ++n)
            #pragma unroll
            for (int q = 0; q < 4; ++q) {
                const int r = r0 + wr * 32 + m * 16 + (l >> 4) * 4 + q;
                const int c = c0 + wc * 32 + n * 16 + lr;
                float v = acc[m][n][q] + bz[n];
                const size_t oa = (size_t)r * Dm + c;
                if (mode == 1) {
                    Ofp[oa] = v;
                } else {
                    const unsigned short hh = bf16h(v);
                    Ohi[oa] = hh;
                    Olo[oa] = bf16h(v - bf16f(hh));
                }
            }
}

// ---------------------------------------------------------------------------
// g[p, h] = sum_k rel_pe[p, k] * wse[h, k]    (1024 x 16), fp32
// ---------------------------------------------------------------------------
__global__ __launch_bounds__(256) void g_kernel(
    const float* __restrict__ rel_pe, const float* __restrict__ WSE,
    float* __restrict__ G)
{
    __shared__ float rp[1024];
    const int t = threadIdx.x;
    const int p = blockIdx.x;
    ((float4*)rp)[t] = ((const float4*)(rel_pe + p * Dm))[t];
    __syncthreads();
    const int h = t >> 4, part = t & 15;
    float s = 0.f;
    #pragma unroll 8
    for (int m = 0; m < 64; ++m) {
        const int kk = part + (m << 4);
        s += rp[kk] * WSE[h * Dm + kk];
    }
    s += __shfl_down(s, 8, 16);
    s += __shfl_down(s, 4, 16);
    s += __shfl_down(s, 2, 16);
    s += __shfl_down(s, 1, 16);
    if (part == 0) G[p * 16 + h] = s;
}

// ---------------------------------------------------------------------------
// attn4: MFMA attention (attn3 + inline V transpose; no Vt global buffer).
// Block = (b,h,ihalf): 64 q-rows x 128 kv. 4 waves, 16-row strips.
// QK^T and PV via 16x16x32 bf16 MFMA hi/lo 3-pass; softmax in fragments.
// V staged straight from global [j][hd] with in-LDS transpose to [hd][j].
// ---------------------------------------------------------------------------
__global__ __launch_bounds__(256) void attn4_kernel(
    const ushort_t* __restrict__ NQhi, const ushort_t* __restrict__ NQlo,
    const ushort_t* __restrict__ Khi,  const ushort_t* __restrict__ Klo,
    const ushort_t* __restrict__ Vhi,  const ushort_t* __restrict__ Vlo,
    const float* __restrict__ G, const int* __restrict__ SM,
    const float* __restrict__ spk_emb,
    ushort_t* __restrict__ Ahi, ushort_t* __restrict__ Alo)
{
    __shared__ __align__(16) ushort_t KP[18432];  // Kh|Kl, later Ph|Pl
    __shared__ __align__(16) ushort_t QV[9216];   // Qh|Ql, later Vth|Vtl
    __shared__ float cp[128];
    __shared__ float Es[128];      // E[r][m] = Es[r*2+m]
    __shared__ float se[128];
    __shared__ float zin[64];
    __shared__ unsigned SMw[256];  // [r][word]

    const int blk = blockIdx.x, n = blk >> 1, ihalf = blk & 1;
    const int b = n >> 4, h = n & 15;
    const int t = threadIdx.x, w = t >> 6, l = t & 63;
    const int lc = l & 15, lg = l >> 4;
    const int r0w = w * 16;

    ushort_t* Kh = KP;            ushort_t* Kl = KP + 9216;
    ushort_t* Qh = QV;            ushort_t* Ql = QV + 4608;

    // ---- phase 0: staging ----
    #pragma unroll
    for (int it = 0; it < 2; ++it) {           // Q: 64 rows x 8 chunks
        const int task = it * 256 + t;
        const int r = task >> 3, col = (task & 7) * 8;
        const size_t g0 = (size_t)((ihalf * 64 + r) * 8 + b) * 1024 + h * 64 + col;
        *(int4*)&Qh[r * 72 + col] = *(const int4*)(NQhi + g0);
        *(int4*)&Ql[r * 72 + col] = *(const int4*)(NQlo + g0);
    }
    #pragma unroll
    for (int it = 0; it < 4; ++it) {           // K: 128 rows x 8 chunks
        const int task = it * 256 + t;
        const int j = task >> 3, col = (task & 7) * 8;
        const size_t g0 = (size_t)(j * 8 + b) * 1024 + h * 64 + col;
        *(int4*)&Kh[j * 72 + col] = *(const int4*)(Khi + g0);
        *(int4*)&Kl[j * 72 + col] = *(const int4*)(Klo + g0);
    }
    {   // spk-mask bit pack: r = t>>2, word = t&3
        const int r = t >> 2, wd = t & 3;
        const int i_glob = ihalf * 64 + r;
        const int* sp = SM + ((size_t)b * 128 + i_glob) * 128 + wd * 32;
        unsigned bits = 0;
        #pragma unroll
        for (int e8 = 0; e8 < 8; ++e8) {
            const int4 v = *(const int4*)(sp + e8 * 4);
            bits |= (v.x != 0 ? 1u : 0u) << (e8 * 4 + 0);
            bits |= (v.y != 0 ? 1u : 0u) << (e8 * 4 + 1);
            bits |= (v.z != 0 ? 1u : 0u) << (e8 * 4 + 2);
            bits |= (v.w != 0 ? 1u : 0u) << (e8 * 4 + 3);
        }
        SMw[r * 4 + wd] = bits;
    }
    if (t < 128) {
        cp[t] = G[((((t >> 4) << 7) + ((t & 15) << 3) + b) << 4) + h];
        se[t] = spk_emb[(t >> 6) * 1024 + h * 64 + (t & 63)];
    }
    __syncthreads();

    // ---- phase 1: QK^T MFMA + speaker dots E ----
    f32x4 acc[8];
    #pragma unroll
    for (int jt = 0; jt < 8; ++jt) acc[jt] = (f32x4){0.f, 0.f, 0.f, 0.f};
    #pragma unroll
    for (int ks = 0; ks < 2; ++ks) {
        const bf16x8 a_h = *(bf16x8*)&Qh[(r0w + lc) * 72 + ks * 32 + lg * 8];
        const bf16x8 a_l = *(bf16x8*)&Ql[(r0w + lc) * 72 + ks * 32 + lg * 8];
        #pragma unroll
        for (int jt = 0; jt < 8; ++jt) {
            const bf16x8 b_h = *(bf16x8*)&Kh[(jt * 16 + lc) * 72 + ks * 32 + lg * 8];
            const bf16x8 b_l = *(bf16x8*)&Kl[(jt * 16 + lc) * 72 + ks * 32 + lg * 8];
            acc[jt] = __builtin_amdgcn_mfma_f32_16x16x32_bf16(a_h, b_h, acc[jt], 0, 0, 0);
            acc[jt] = __builtin_amdgcn_mfma_f32_16x16x32_bf16(a_l, b_h, acc[jt], 0, 0, 0);
            acc[jt] = __builtin_amdgcn_mfma_f32_16x16x32_bf16(a_h, b_l, acc[jt], 0, 0, 0);
        }
    }
    {   // E[r][m] = new_q[r] . spk_emb[m] (per-head slice)
        const int r = t >> 2, m = (t >> 1) & 1, half = t & 1;
        float v = 0.f;
        #pragma unroll
        for (int e = 0; e < 32; ++e) {
            const int hd = half * 32 + e;
            const float qf = bf16f(Qh[r * 72 + hd]) + bf16f(Ql[r * 72 + hd]);
            v += qf * se[m * 64 + hd];
        }
        v += __shfl_xor(v, 1);
        if (half == 0) Es[r * 2 + m] = v;
    }
    __syncthreads();

    // ---- phase 2: softmax in fragments; write P hi/lo; stage V chunk 0
    //      (V read [j][hd] from global, transposed into LDS [hd][j]) ----
    ushort_t* Ph = KP;            ushort_t* Pl = KP + 8704;
    ushort_t* Vth = QV;           ushort_t* Vtl = QV + 4608;
    #pragma unroll
    for (int q = 0; q < 4; ++q) {
        const int r = r0w + lg * 4 + q;
        const int i_glob = ihalf * 64 + r;
        const float e0 = Es[r * 2 + 0], e1 = Es[r * 2 + 1];
        float s[8];
        #pragma unroll
        for (int jt = 0; jt < 8; ++jt) {
            const int j = jt * 16 + lc;
            if (j > i_glob) {
                s[jt] = 1e-30f;
            } else {
                const unsigned bit = (SMw[r * 4 + (jt >> 1)] >> ((jt & 1) * 16 + lc)) & 1u;
                s[jt] = (acc[jt][q] + (bit ? e1 : e0) + cp[127 + j - i_glob]) * 0.125f;
            }
        }
        float mx = s[0];
        #pragma unroll
        for (int jt = 1; jt < 8; ++jt) mx = fmaxf(mx, s[jt]);
        mx = fmaxf(mx, __shfl_xor(mx, 1));
        mx = fmaxf(mx, __shfl_xor(mx, 2));
        mx = fmaxf(mx, __shfl_xor(mx, 4));
        mx = fmaxf(mx, __shfl_xor(mx, 8));
        float zs = 0.f;
        #pragma unroll
        for (int jt = 0; jt < 8; ++jt) { s[jt] = __expf(s[jt] - mx); zs += s[jt]; }
        zs += __shfl_xor(zs, 1);
        zs += __shfl_xor(zs, 2);
        zs += __shfl_xor(zs, 4);
        zs += __shfl_xor(zs, 8);
        if (lc == 0) zin[r] = 1.f / zs;
        #pragma unroll
        for (int jt = 0; jt < 8; ++jt) {
            const unsigned short hh = bf16h(s[jt]);
            Ph[r * 136 + jt * 16 + lc] = hh;
            Pl[r * 136 + jt * 16 + lc] = bf16h(s[jt] - bf16f(hh));
        }
    }
    #pragma unroll
    for (int it = 0; it < 2; ++it) {           // V chunk 0: kv rows 0..63
        const int task = it * 256 + t;
        const int j = task >> 3, hc = (task & 7) * 8;
        const size_t gv = (size_t)(j * 8 + b) * 1024 + h * 64 + hc;
        int4 uh = *(const int4*)(Vhi + gv);
        int4 ul = *(const int4*)(Vlo + gv);
        const ushort_t* ph8 = (const ushort_t*)&uh;
        const ushort_t* pl8 = (const ushort_t*)&ul;
        #pragma unroll
        for (int e = 0; e < 8; ++e) {
            Vth[(hc + e) * 72 + j] = ph8[e];
            Vtl[(hc + e) * 72 + j] = pl8[e];
        }
    }
    __syncthreads();

    // ---- phase 3: PV chunk 0 ----
    f32x4 oacc[4];
    #pragma unroll
    for (int nt = 0; nt < 4; ++nt) oacc[nt] = (f32x4){0.f, 0.f, 0.f, 0.f};
    #pragma unroll
    for (int ks = 0; ks < 2; ++ks) {
        const bf16x8 a_h = *(bf16x8*)&Ph[(r0w + lc) * 136 + ks * 32 + lg * 8];
        const bf16x8 a_l = *(bf16x8*)&Pl[(r0w + lc) * 136 + ks * 32 + lg * 8];
        #pragma unroll
        for (int nt = 0; nt < 4; ++nt) {
            const bf16x8 b_h = *(bf16x8*)&Vth[(nt * 16 + lc) * 72 + ks * 32 + lg * 8];
            const bf16x8 b_l = *(bf16x8*)&Vtl[(nt * 16 + lc) * 72 + ks * 32 + lg * 8];
            oacc[nt] = __builtin_amdgcn_mfma_f32_16x16x32_bf16(a_h, b_h, oacc[nt], 0, 0, 0);
            oacc[nt] = __builtin_amdgcn_mfma_f32_16x16x32_bf16(a_l, b_h, oacc[nt], 0, 0, 0);
            oacc[nt] = __builtin_amdgcn_mfma_f32_16x16x32_bf16(a_h, b_l, oacc[nt], 0, 0, 0);
        }
    }
    __syncthreads();

    // ---- phase 4: stage V chunk 1 (kv rows 64..127, transposed) ----
    #pragma unroll
    for (int it = 0; it < 2; ++it) {
        const int task = it * 256 + t;
        const int jl = task >> 3, hc = (task & 7) * 8;
        const size_t gv = (size_t)((64 + jl) * 8 + b) * 1024 + h * 64 + hc;
        int4 uh = *(const int4*)(Vhi + gv);
        int4 ul = *(const int4*)(Vlo + gv);
        const ushort_t* ph8 = (const ushort_t*)&uh;
        const ushort_t* pl8 = (const ushort_t*)&ul;
        #pragma unroll
        for (int e = 0; e < 8; ++e) {
            Vth[(hc + e) * 72 + jl] = ph8[e];
            Vtl[(hc + e) * 72 + jl] = pl8[e];
        }
    }
    __syncthreads();

    // ---- phase 5: PV chunk 1 + epilogue ----
    #pragma unroll
    for (int ks = 0; ks < 2; ++ks) {
        const bf16x8 a_h = *(bf16x8*)&Ph[(r0w + lc) * 136 + 64 + ks * 32 + lg * 8];
        const bf16x8 a_l = *(bf16x8*)&Pl[(r0w + lc) * 136 + 64 + ks * 32 + lg * 8];
        #pragma unroll
        for (int nt = 0; nt < 4; ++nt) {
            const bf16x8 b_h = *(bf16x8*)&Vth[(nt * 16 + lc) * 72 + ks * 32 + lg * 8];
            const bf16x8 b_l = *(bf16x8*)&Vtl[(nt * 16 + lc) * 72 + ks * 32 + lg * 8];
            oacc[nt] = __builtin_amdgcn_mfma_f32_16x16x32_bf16(a_h, b_h, oacc[nt], 0, 0, 0);
            oacc[nt] = __builtin_amdgcn_mfma_f32_16x16x32_bf16(a_l, b_h, oacc[nt], 0, 0, 0);
            oacc[nt] = __builtin_amdgcn_mfma_f32_16x16x32_bf16(a_h, b_l, oacc[nt], 0, 0, 0);
        }
    }
    #pragma unroll
    for (int nt = 0; nt < 4; ++nt)
        #pragma unroll
        for (int q = 0; q < 4; ++q) {
            const int r = r0w + lg * 4 + q;
            const float val = oacc[nt][q] * zin[r];
            const int i_glob = ihalf * 64 + r;
            const size_t oa = (size_t)(i_glob * 8 + b) * 1024 + h * 64 + nt * 16 + lc;
            const unsigned short hh = bf16h(val);
            Ahi[oa] = hh;
            Alo[oa] = bf16h(val - bf16f(hh));
        }
}

// ---------------------------------------------------------------------------
extern "C" void kernel_launch(void* const* d_in, const int* in_sizes, int n_in,
                              void* d_out, int out_size, void* d_ws, size_t ws_size,
                              hipStream_t stream) {
    (void)in_sizes; (void)n_in; (void)out_size; (void)ws_size;
    const float* query   = (const float*)d_in[0];
    const float* rel_pe  = (const float*)d_in[1];
    const float* Wq      = (const float*)d_in[3];
    const float* Wk      = (const float*)d_in[4];
    const float* Wv      = (const float*)d_in[5];
    const float* Wr      = (const float*)d_in[6];
    const float* Wo      = (const float*)d_in[7];
    const float* spk_emb = (const float*)d_in[8];
    const int*   SM      = (const int*)d_in[10];
    float* out = (float*)d_out;

    const size_t MB1 = 1u << 20;
    ushort_t* us = (ushort_t*)d_ws;
    ushort_t* qhi  = us + 0 * MB1;   ushort_t* qlo  = us + 1 * MB1;
    ushort_t* wqhi = us + 2 * MB1;   ushort_t* wqlo = us + 3 * MB1;
    ushort_t* wkhi = us + 4 * MB1;   ushort_t* wklo = us + 5 * MB1;
    ushort_t* wvhi = us + 6 * MB1;   ushort_t* wvlo = us + 7 * MB1;
    ushort_t* wohi = us + 8 * MB1;   ushort_t* wolo = us + 9 * MB1;
    ushort_t* nqhi = us + 10 * MB1;  ushort_t* nqlo = us + 11 * MB1;
    ushort_t* khi  = us + 12 * MB1;  ushort_t* klo  = us + 13 * MB1;
    ushort_t* vhi  = us + 14 * MB1;  ushort_t* vlo  = us + 15 * MB1;
    float* WSE = (float*)(us + 16 * MB1);
    float* Gp  = WSE + 16384;
    ushort_t* atthi = qhi;   // query dead after QKV gemm
    ushort_t* attlo = qlo;

    convert6_kernel<<<dim3(512, 1, 6), 256, 0, stream>>>(
        query, Wq, Wk, Wv, Wo,
        qhi, qlo, wqhi, wqlo, wkhi, wklo, wvhi, wvlo, wohi, wolo,
        Wr, spk_emb, WSE);

    gemm3_kernel<<<dim3(16, 16, 3), 256, 0, stream>>>(
        qhi, qlo, wqhi, wqlo, wkhi, wklo, wvhi, wvlo,
        nqhi, nqlo, khi, klo, vhi, vlo, nullptr, spk_emb, 0);

    g_kernel<<<1024, 256, 0, stream>>>(rel_pe, WSE, Gp);

    attn4_kernel<<<256, 256, 0, stream>>>(
        nqhi, nqlo, khi, klo, vhi, vlo, Gp, SM, spk_emb, atthi, attlo);

    gemm3_kernel<<<dim3(16, 16, 1), 256, 0, stream>>>(
        atthi, attlo, wohi, wolo, wohi, wolo, wohi, wolo,
        nullptr, nullptr, nullptr, nullptr, nullptr, nullptr,
        out, nullptr, 1);
}

// Round 10
// 157.591 us; speedup vs baseline: 1.2722x; 1.0674x over previous
//
#include <hip/hip_runtime.h>

#define Dm 1024
#define Lq 128
#define Bq 8
#define Hh 16
#define HDim 64

typedef __attribute__((ext_vector_type(8))) short bf16x8;
typedef __attribute__((ext_vector_type(4))) float f32x4;
typedef unsigned short ushort_t;

__device__ __forceinline__ unsigned short bf16h(float x) {
    unsigned u = __float_as_uint(x);
    return (unsigned short)((u + 0x7FFFu + ((u >> 16) & 1u)) >> 16);
}
__device__ __forceinline__ float bf16f(unsigned short s) {
    return __uint_as_float(((unsigned)s) << 16);
}

// ---------------------------------------------------------------------------
// convert7: z=0 -> query to (hi,lo); z=1..4 -> {Wq,Wk,Wv,Wo} to hi ONLY
// (weights are always the MFMA B-operand; 2-pass drops a_hi*b_lo so b_lo is
// never consumed); z=5 (x<64) -> wse[h,k] = sum_hd Wr[h*64+hd,k]*spk_emb[0,..]
// ---------------------------------------------------------------------------
__global__ __launch_bounds__(256) void convert7_kernel(
    const float* __restrict__ s0, const float* __restrict__ s1, const float* __restrict__ s2,
    const float* __restrict__ s3, const float* __restrict__ s4,
    ushort_t* __restrict__ d0h, ushort_t* __restrict__ d0l,
    ushort_t* __restrict__ d1h, ushort_t* __restrict__ d2h,
    ushort_t* __restrict__ d3h, ushort_t* __restrict__ d4h,
    const float* __restrict__ Wr, const float* __restrict__ spk_emb,
    float* __restrict__ WSE)
{
    const int z = blockIdx.z;
    const int t = threadIdx.x;
    if (z == 5) {
        if (blockIdx.x >= 64) return;
        __shared__ float se[64];
        const int h = blockIdx.x >> 2;
        const int k = (blockIdx.x & 3) * 256 + t;
        if (t < 64) se[t] = spk_emb[h * 64 + t];
        __syncthreads();
        float s = 0.f;
        #pragma unroll 8
        for (int hd = 0; hd < 64; ++hd)
            s += Wr[(h * 64 + hd) * Dm + k] * se[hd];
        WSE[h * Dm + k] = s;
        return;
    }
    const float* src = (z == 0) ? s0 : (z == 1) ? s1 : (z == 2) ? s2 : (z == 3) ? s3 : s4;
    ushort_t* dh = (z == 0) ? d0h : (z == 1) ? d1h : (z == 2) ? d2h : (z == 3) ? d3h : d4h;
    const bool wlo = (z == 0);
    const int idx = (blockIdx.x * 256 + t) * 8;
    const float4 a = *(const float4*)(src + idx);
    const float4 b = *(const float4*)(src + idx + 4);
    float xs[8] = {a.x, a.y, a.z, a.w, b.x, b.y, b.z, b.w};
    unsigned hp[4], lp[4];
    #pragma unroll
    for (int e = 0; e < 4; ++e) {
        unsigned short h0 = bf16h(xs[2*e]), h1 = bf16h(xs[2*e+1]);
        hp[e] = (unsigned)h0 | ((unsigned)h1 << 16);
        if (wlo) {
            unsigned short l0 = bf16h(xs[2*e]   - bf16f(h0));
            unsigned short l1 = bf16h(xs[2*e+1] - bf16f(h1));
            lp[e] = (unsigned)l0 | ((unsigned)l1 << 16);
        }
    }
    *(int4*)(dh + idx) = *(int4*)hp;
    if (wlo) *(int4*)(d0l + idx) = *(int4*)lp;
}

// ---------------------------------------------------------------------------
// gemm2p: OUT[r,c] = sum_k X[r,k]*W[c,k] via bf16 hi/lo 2-PASS MFMA
// (hi*hi + lo*hi; W lo never loaded). 64x64 tile, 4 waves (2x2 of 32x32),
// BK=32, double-buffered reg-staged LDS (24 KB). mode 0: bf16 hi(+lo if ptr)
// outputs; z selects W/O; bias on z==0. mode 1: fp32 out.
// ---------------------------------------------------------------------------
__global__ __launch_bounds__(256) void gemm2p_kernel(
    const ushort_t* __restrict__ Xhi, const ushort_t* __restrict__ Xlo,
    const ushort_t* __restrict__ W0h, const ushort_t* __restrict__ W1h,
    const ushort_t* __restrict__ W2h,
    ushort_t* __restrict__ O0h, ushort_t* __restrict__ O0l,
    ushort_t* __restrict__ O1h, ushort_t* __restrict__ O1l,
    ushort_t* __restrict__ O2h, ushort_t* __restrict__ O2l,
    float* __restrict__ Ofp, const float* __restrict__ bias, int mode)
{
    const int z = blockIdx.z;
    const ushort_t* Wh = (z == 0) ? W0h : (z == 1) ? W1h : W2h;
    ushort_t* Ohi = (z == 0) ? O0h : (z == 1) ? O1h : O2h;
    ushort_t* Olo = (z == 0) ? O0l : (z == 1) ? O1l : O2l;

    __shared__ __align__(16) short Axh[2][64][32];
    __shared__ __align__(16) short Axl[2][64][32];
    __shared__ __align__(16) short Bwh[2][64][32];

    const int t = threadIdx.x, w = t >> 6, l = t & 63;
    const int r0 = blockIdx.y * 64, c0 = blockIdx.x * 64;
    const int wr = w >> 1, wc = w & 1;
    const int srow = t >> 2, sk = (t & 3) * 8;
    const int lr = l & 15, lk = (l >> 4) * 8;

    const size_t xbase = (size_t)(r0 + srow) * Dm + sk;
    const size_t wbase = (size_t)(c0 + srow) * Dm + sk;

    f32x4 acc[2][2];
    #pragma unroll
    for (int m = 0; m < 2; ++m)
        #pragma unroll
        for (int n = 0; n < 2; ++n)
            acc[m][n] = (f32x4){0.f, 0.f, 0.f, 0.f};

    {
        int4 xh = *(const int4*)(Xhi + xbase);
        int4 xl = *(const int4*)(Xlo + xbase);
        int4 wh = *(const int4*)(Wh + wbase);
        *(int4*)&Axh[0][srow][sk] = xh;
        *(int4*)&Axl[0][srow][sk] = xl;
        *(int4*)&Bwh[0][srow][sk] = wh;
    }
    __syncthreads();

    int cur = 0;
    for (int step = 0; step < 32; ++step) {
        int4 nxh, nxl, nwh;
        const bool more = (step < 31);
        if (more) {
            const int kt = (step + 1) * 32;
            nxh = *(const int4*)(Xhi + xbase + kt);
            nxl = *(const int4*)(Xlo + xbase + kt);
            nwh = *(const int4*)(Wh + wbase + kt);
        }
        bf16x8 ah[2], al[2], bh[2];
        #pragma unroll
        for (int m = 0; m < 2; ++m) {
            ah[m] = *(bf16x8*)&Axh[cur][wr * 32 + m * 16 + lr][lk];
            al[m] = *(bf16x8*)&Axl[cur][wr * 32 + m * 16 + lr][lk];
        }
        #pragma unroll
        for (int n = 0; n < 2; ++n)
            bh[n] = *(bf16x8*)&Bwh[cur][wc * 32 + n * 16 + lr][lk];
        #pragma unroll
        for (int m = 0; m < 2; ++m)
            #pragma unroll
            for (int n = 0; n < 2; ++n) {
                acc[m][n] = __builtin_amdgcn_mfma_f32_16x16x32_bf16(ah[m], bh[n], acc[m][n], 0, 0, 0);
                acc[m][n] = __builtin_amdgcn_mfma_f32_16x16x32_bf16(al[m], bh[n], acc[m][n], 0, 0, 0);
            }
        if (more) {
            const int nb = cur ^ 1;
            *(int4*)&Axh[nb][srow][sk] = nxh;
            *(int4*)&Axl[nb][srow][sk] = nxl;
            *(int4*)&Bwh[nb][srow][sk] = nwh;
        }
        __syncthreads();
        cur ^= 1;
    }

    float bz[2] = {0.f, 0.f};
    if (mode == 0 && z == 0 && bias != nullptr) {
        #pragma unroll
        for (int n = 0; n < 2; ++n)
            bz[n] = bias[c0 + wc * 32 + n * 16 + lr];
    }
    #pragma unroll
    for (int m = 0; m < 2; ++m)
        #pragma unroll
        for (int n = 0; n < 2; ++n)
            #pragma unroll
            for (int q = 0; q < 4; ++q) {
                const int r = r0 + wr * 32 + m * 16 + (l >> 4) * 4 + q;
                const int c = c0 + wc * 32 + n * 16 + lr;
                float v = acc[m][n][q] + bz[n];
                const size_t oa = (size_t)r * Dm + c;
                if (mode == 1) {
                    Ofp[oa] = v;
                } else {
                    const unsigned short hh = bf16h(v);
                    Ohi[oa] = hh;
                    if (Olo != nullptr) Olo[oa] = bf16h(v - bf16f(hh));
                }
            }
}

// ---------------------------------------------------------------------------
// g[p, h] = sum_k rel_pe[p, k] * wse[h, k]    (1024 x 16), fp32
// ---------------------------------------------------------------------------
__global__ __launch_bounds__(256) void g_kernel(
    const float* __restrict__ rel_pe, const float* __restrict__ WSE,
    float* __restrict__ G)
{
    __shared__ float rp[1024];
    const int t = threadIdx.x;
    const int p = blockIdx.x;
    ((float4*)rp)[t] = ((const float4*)(rel_pe + p * Dm))[t];
    __syncthreads();
    const int h = t >> 4, part = t & 15;
    float s = 0.f;
    #pragma unroll 8
    for (int m = 0; m < 64; ++m) {
        const int kk = part + (m << 4);
        s += rp[kk] * WSE[h * Dm + kk];
    }
    s += __shfl_down(s, 8, 16);
    s += __shfl_down(s, 4, 16);
    s += __shfl_down(s, 2, 16);
    s += __shfl_down(s, 1, 16);
    if (part == 0) G[p * 16 + h] = s;
}

// ---------------------------------------------------------------------------
// attn5: MFMA attention, 2-pass hi/lo (K and V lo never staged).
// Block = (b,h,ihalf): 64 q-rows x 128 kv. 4 waves, 16-row strips.
// QK^T: mfma(Qh,Kh)+mfma(Ql,Kh). PV: mfma(Ph,Vt)+mfma(Pl,Vt).
// V staged from global [j][hd] with in-LDS transpose to [hd][j] (hi only).
// ---------------------------------------------------------------------------
__global__ __launch_bounds__(256) void attn5_kernel(
    const ushort_t* __restrict__ NQhi, const ushort_t* __restrict__ NQlo,
    const ushort_t* __restrict__ Khi,
    const ushort_t* __restrict__ Vhi,
    const float* __restrict__ G, const int* __restrict__ SM,
    const float* __restrict__ spk_emb,
    ushort_t* __restrict__ Ahi, ushort_t* __restrict__ Alo)
{
    __shared__ __align__(16) ushort_t KP[17408];  // Kh (9216), later Ph|Pl (8704+8704)
    __shared__ __align__(16) ushort_t QV[9216];   // Qh|Ql, later Vth (4608)
    __shared__ float cp[128];
    __shared__ float Es[128];      // E[r][m] = Es[r*2+m]
    __shared__ float se[128];
    __shared__ float zin[64];
    __shared__ unsigned SMw[256];  // [r][word]

    const int blk = blockIdx.x, n = blk >> 1, ihalf = blk & 1;
    const int b = n >> 4, h = n & 15;
    const int t = threadIdx.x, w = t >> 6, l = t & 63;
    const int lc = l & 15, lg = l >> 4;
    const int r0w = w * 16;

    ushort_t* Kh = KP;
    ushort_t* Qh = QV;            ushort_t* Ql = QV + 4608;

    // ---- phase 0: staging ----
    #pragma unroll
    for (int it = 0; it < 2; ++it) {           // Q: 64 rows x 8 chunks (hi+lo)
        const int task = it * 256 + t;
        const int r = task >> 3, col = (task & 7) * 8;
        const size_t g0 = (size_t)((ihalf * 64 + r) * 8 + b) * 1024 + h * 64 + col;
        *(int4*)&Qh[r * 72 + col] = *(const int4*)(NQhi + g0);
        *(int4*)&Ql[r * 72 + col] = *(const int4*)(NQlo + g0);
    }
    #pragma unroll
    for (int it = 0; it < 4; ++it) {           // K: 128 rows x 8 chunks (hi only)
        const int task = it * 256 + t;
        const int j = task >> 3, col = (task & 7) * 8;
        const size_t g0 = (size_t)(j * 8 + b) * 1024 + h * 64 + col;
        *(int4*)&Kh[j * 72 + col] = *(const int4*)(Khi + g0);
    }
    {   // spk-mask bit pack: r = t>>2, word = t&3
        const int r = t >> 2, wd = t & 3;
        const int i_glob = ihalf * 64 + r;
        const int* sp = SM + ((size_t)b * 128 + i_glob) * 128 + wd * 32;
        unsigned bits = 0;
        #pragma unroll
        for (int e8 = 0; e8 < 8; ++e8) {
            const int4 v = *(const int4*)(sp + e8 * 4);
            bits |= (v.x != 0 ? 1u : 0u) << (e8 * 4 + 0);
            bits |= (v.y != 0 ? 1u : 0u) << (e8 * 4 + 1);
            bits |= (v.z != 0 ? 1u : 0u) << (e8 * 4 + 2);
            bits |= (v.w != 0 ? 1u : 0u) << (e8 * 4 + 3);
        }
        SMw[r * 4 + wd] = bits;
    }
    if (t < 128) {
        cp[t] = G[((((t >> 4) << 7) + ((t & 15) << 3) + b) << 4) + h];
        se[t] = spk_emb[(t >> 6) * 1024 + h * 64 + (t & 63)];
    }
    __syncthreads();

    // ---- phase 1: QK^T MFMA (2-pass) + speaker dots E ----
    f32x4 acc[8];
    #pragma unroll
    for (int jt = 0; jt < 8; ++jt) acc[jt] = (f32x4){0.f, 0.f, 0.f, 0.f};
    #pragma unroll
    for (int ks = 0; ks < 2; ++ks) {
        const bf16x8 a_h = *(bf16x8*)&Qh[(r0w + lc) * 72 + ks * 32 + lg * 8];
        const bf16x8 a_l = *(bf16x8*)&Ql[(r0w + lc) * 72 + ks * 32 + lg * 8];
        #pragma unroll
        for (int jt = 0; jt < 8; ++jt) {
            const bf16x8 b_h = *(bf16x8*)&Kh[(jt * 16 + lc) * 72 + ks * 32 + lg * 8];
            acc[jt] = __builtin_amdgcn_mfma_f32_16x16x32_bf16(a_h, b_h, acc[jt], 0, 0, 0);
            acc[jt] = __builtin_amdgcn_mfma_f32_16x16x32_bf16(a_l, b_h, acc[jt], 0, 0, 0);
        }
    }
    {   // E[r][m] = new_q[r] . spk_emb[m] (per-head slice)
        const int r = t >> 2, m = (t >> 1) & 1, half = t & 1;
        float v = 0.f;
        #pragma unroll
        for (int e = 0; e < 32; ++e) {
            const int hd = half * 32 + e;
            const float qf = bf16f(Qh[r * 72 + hd]) + bf16f(Ql[r * 72 + hd]);
            v += qf * se[m * 64 + hd];
        }
        v += __shfl_xor(v, 1);
        if (half == 0) Es[r * 2 + m] = v;
    }
    __syncthreads();

    // ---- phase 2: softmax in fragments; write P hi/lo; stage V chunk 0 ----
    ushort_t* Ph = KP;            ushort_t* Pl = KP + 8704;
    ushort_t* Vth = QV;
    #pragma unroll
    for (int q = 0; q < 4; ++q) {
        const int r = r0w + lg * 4 + q;
        const int i_glob = ihalf * 64 + r;
        const float e0 = Es[r * 2 + 0], e1 = Es[r * 2 + 1];
        float s[8];
        #pragma unroll
        for (int jt = 0; jt < 8; ++jt) {
            const int j = jt * 16 + lc;
            if (j > i_glob) {
                s[jt] = 1e-30f;
            } else {
                const unsigned bit = (SMw[r * 4 + (jt >> 1)] >> ((jt & 1) * 16 + lc)) & 1u;
                s[jt] = (acc[jt][q] + (bit ? e1 : e0) + cp[127 + j - i_glob]) * 0.125f;
            }
        }
        float mx = s[0];
        #pragma unroll
        for (int jt = 1; jt < 8; ++jt) mx = fmaxf(mx, s[jt]);
        mx = fmaxf(mx, __shfl_xor(mx, 1));
        mx = fmaxf(mx, __shfl_xor(mx, 2));
        mx = fmaxf(mx, __shfl_xor(mx, 4));
        mx = fmaxf(mx, __shfl_xor(mx, 8));
        float zs = 0.f;
        #pragma unroll
        for (int jt = 0; jt < 8; ++jt) { s[jt] = __expf(s[jt] - mx); zs += s[jt]; }
        zs += __shfl_xor(zs, 1);
        zs += __shfl_xor(zs, 2);
        zs += __shfl_xor(zs, 4);
        zs += __shfl_xor(zs, 8);
        if (lc == 0) zin[r] = 1.f / zs;
        #pragma unroll
        for (int jt = 0; jt < 8; ++jt) {
            const unsigned short hh = bf16h(s[jt]);
            Ph[r * 136 + jt * 16 + lc] = hh;
            Pl[r * 136 + jt * 16 + lc] = bf16h(s[jt] - bf16f(hh));
        }
    }
    #pragma unroll
    for (int it = 0; it < 2; ++it) {           // V chunk 0: kv rows 0..63 (hi only)
        const int task = it * 256 + t;
        const int j = task >> 3, hc = (task & 7) * 8;
        const size_t gv = (size_t)(j * 8 + b) * 1024 + h * 64 + hc;
        int4 uh = *(const int4*)(Vhi + gv);
        const ushort_t* ph8 = (const ushort_t*)&uh;
        #pragma unroll
        for (int e = 0; e < 8; ++e)
            Vth[(hc + e) * 72 + j] = ph8[e];
    }
    __syncthreads();

    // ---- phase 3: PV chunk 0 (2-pass) ----
    f32x4 oacc[4];
    #pragma unroll
    for (int nt = 0; nt < 4; ++nt) oacc[nt] = (f32x4){0.f, 0.f, 0.f, 0.f};
    #pragma unroll
    for (int ks = 0; ks < 2; ++ks) {
        const bf16x8 a_h = *(bf16x8*)&Ph[(r0w + lc) * 136 + ks * 32 + lg * 8];
        const bf16x8 a_l = *(bf16x8*)&Pl[(r0w + lc) * 136 + ks * 32 + lg * 8];
        #pragma unroll
        for (int nt = 0; nt < 4; ++nt) {
            const bf16x8 b_h = *(bf16x8*)&Vth[(nt * 16 + lc) * 72 + ks * 32 + lg * 8];
            oacc[nt] = __builtin_amdgcn_mfma_f32_16x16x32_bf16(a_h, b_h, oacc[nt], 0, 0, 0);
            oacc[nt] = __builtin_amdgcn_mfma_f32_16x16x32_bf16(a_l, b_h, oacc[nt], 0, 0, 0);
        }
    }
    __syncthreads();

    // ---- phase 4: stage V chunk 1 (kv rows 64..127, transposed, hi only) ----
    #pragma unroll
    for (int it = 0; it < 2; ++it) {
        const int task = it * 256 + t;
        const int jl = task >> 3, hc = (task & 7) * 8;
        const size_t gv = (size_t)((64 + jl) * 8 + b) * 1024 + h * 64 + hc;
        int4 uh = *(const int4*)(Vhi + gv);
        const ushort_t* ph8 = (const ushort_t*)&uh;
        #pragma unroll
        for (int e = 0; e < 8; ++e)
            Vth[(hc + e) * 72 + jl] = ph8[e];
    }
    __syncthreads();

    // ---- phase 5: PV chunk 1 + epilogue ----
    #pragma unroll
    for (int ks = 0; ks < 2; ++ks) {
        const bf16x8 a_h = *(bf16x8*)&Ph[(r0w + lc) * 136 + 64 + ks * 32 + lg * 8];
        const bf16x8 a_l = *(bf16x8*)&Pl[(r0w + lc) * 136 + 64 + ks * 32 + lg * 8];
        #pragma unroll
        for (int nt = 0; nt < 4; ++nt) {
            const bf16x8 b_h = *(bf16x8*)&Vth[(nt * 16 + lc) * 72 + ks * 32 + lg * 8];
            oacc[nt] = __builtin_amdgcn_mfma_f32_16x16x32_bf16(a_h, b_h, oacc[nt], 0, 0, 0);
            oacc[nt] = __builtin_amdgcn_mfma_f32_16x16x32_bf16(a_l, b_h, oacc[nt], 0, 0, 0);
        }
    }
    #pragma unroll
    for (int nt = 0; nt < 4; ++nt)
        #pragma unroll
        for (int q = 0; q < 4; ++q) {
            const int r = r0w + lg * 4 + q;
            const float val = oacc[nt][q] * zin[r];
            const int i_glob = ihalf * 64 + r;
            const size_t oa = (size_t)(i_glob * 8 + b) * 1024 + h * 64 + nt * 16 + lc;
            const unsigned short hh = bf16h(val);
            Ahi[oa] = hh;
            Alo[oa] = bf16h(val - bf16f(hh));
        }
}

// ---------------------------------------------------------------------------
extern "C" void kernel_launch(void* const* d_in, const int* in_sizes, int n_in,
                              void* d_out, int out_size, void* d_ws, size_t ws_size,
                              hipStream_t stream) {
    (void)in_sizes; (void)n_in; (void)out_size; (void)ws_size;
    const float* query   = (const float*)d_in[0];
    const float* rel_pe  = (const float*)d_in[1];
    const float* Wq      = (const float*)d_in[3];
    const float* Wk      = (const float*)d_in[4];
    const float* Wv      = (const float*)d_in[5];
    const float* Wr      = (const float*)d_in[6];
    const float* Wo      = (const float*)d_in[7];
    const float* spk_emb = (const float*)d_in[8];
    const int*   SM      = (const int*)d_in[10];
    float* out = (float*)d_out;

    const size_t MB1 = 1u << 20;
    ushort_t* us = (ushort_t*)d_ws;
    ushort_t* qhi  = us + 0 * MB1;   ushort_t* qlo  = us + 1 * MB1;
    ushort_t* wqhi = us + 2 * MB1;
    ushort_t* wkhi = us + 4 * MB1;
    ushort_t* wvhi = us + 6 * MB1;
    ushort_t* wohi = us + 8 * MB1;
    ushort_t* nqhi = us + 10 * MB1;  ushort_t* nqlo = us + 11 * MB1;
    ushort_t* khi  = us + 12 * MB1;
    ushort_t* vhi  = us + 14 * MB1;
    float* WSE = (float*)(us + 16 * MB1);
    float* Gp  = WSE + 16384;
    ushort_t* atthi = qhi;   // query dead after QKV gemm
    ushort_t* attlo = qlo;

    convert7_kernel<<<dim3(512, 1, 6), 256, 0, stream>>>(
        query, Wq, Wk, Wv, Wo,
        qhi, qlo, wqhi, wkhi, wvhi, wohi,
        Wr, spk_emb, WSE);

    // z=0: NQ (hi+lo, +bias). z=1: K (hi only). z=2: V (hi only).
    gemm2p_kernel<<<dim3(16, 16, 3), 256, 0, stream>>>(
        qhi, qlo, wqhi, wkhi, wvhi,
        nqhi, nqlo, khi, nullptr, vhi, nullptr,
        nullptr, spk_emb, 0);

    g_kernel<<<1024, 256, 0, stream>>>(rel_pe, WSE, Gp);

    attn5_kernel<<<256, 256, 0, stream>>>(
        nqhi, nqlo, khi, vhi, Gp, SM, spk_emb, atthi, attlo);

    gemm2p_kernel<<<dim3(16, 16, 1), 256, 0, stream>>>(
        atthi, attlo, wohi, wohi, wohi,
        nullptr, nullptr, nullptr, nullptr, nullptr, nullptr,
        out, nullptr, 1);
}